// Round 3
// baseline (1759.541 us; speedup 1.0000x reference)
//
#include <hip/hip_runtime.h>
#include <hip/hip_bf16.h>
#include <stdint.h>

// Problem constants (B=1). I/O dtype: fp32 (per reference file — the round-2
// NaN proved the buffers are NOT bf16: misreading fp32 mantissa bits as bf16
// produces NaN patterns; genuine bf16 inputs cannot NaN in this pipeline).
#define S_LEN 2048
#define HID   2048
#define NQH   32
#define NKVH  8
#define HD    64
#define QKV_O 3072      // (32 + 2*8) * 64
#define K_COL 2048      // col offset of K block in qkv row
#define V_COL 2560      // col offset of V block in qkv row

typedef unsigned short ushort_t;
typedef __bf16 bf16x8 __attribute__((ext_vector_type(8)));
typedef float  f32x4  __attribute__((ext_vector_type(4)));

__device__ __forceinline__ ushort_t f2bf(float f) {
    unsigned int x = __float_as_uint(f);
    unsigned int r = (x + 0x7fffu + ((x >> 16) & 1u)) >> 16;   // RNE
    return (ushort_t)r;
}
// packed fp32x2 -> bf16x2 (HW RNE cvt)
__device__ __forceinline__ unsigned int pk_bf16(float a, float b) {
    __hip_bfloat162 h = __float22bfloat162_rn(make_float2(a, b));
    unsigned int r;
    __builtin_memcpy(&r, &h, 4);
    return r;
}
__device__ __forceinline__ void unpack8(float* dst, uint4 u) {
    dst[0] = __uint_as_float(u.x << 16); dst[1] = __uint_as_float(u.x & 0xffff0000u);
    dst[2] = __uint_as_float(u.y << 16); dst[3] = __uint_as_float(u.y & 0xffff0000u);
    dst[4] = __uint_as_float(u.z << 16); dst[5] = __uint_as_float(u.z & 0xffff0000u);
    dst[6] = __uint_as_float(u.w << 16); dst[7] = __uint_as_float(u.w & 0xffff0000u);
}

// ---------------------------------------------------------------------------
// GEMM: C[M][N] = A[M][K] * Bt[N][K]^T, bf16 MFMA core, fp32 accumulate.
// AF32/BF32: source is fp32 (convert to bf16 during LDS staging).
// CF32: store fp32 (else bf16). 128x128 tile, BK=32, 4 waves in 2x2,
// each wave 64x64 via 4x4 mfma_f32_16x16x32_bf16.
// ---------------------------------------------------------------------------
template<bool AF32, bool BF32, bool CF32>
__global__ __launch_bounds__(256) void gemm_bt(
    const void* __restrict__ Ap, const void* __restrict__ Bp,
    void* __restrict__ Cp, int M, int N, int K) {
    // LDS row stride 40 elems = 80 B: 16B-aligned, 2-way bank aliasing (free)
    __shared__ ushort_t As[128][40];
    __shared__ ushort_t Bs[128][40];

    const int t    = threadIdx.x;
    const int wave = t >> 6;
    const int lane = t & 63;
    const int quad = lane >> 4;
    const int l16  = lane & 15;
    const int wm   = (wave >> 1) << 6;
    const int wn   = (wave & 1)  << 6;
    const int bm   = blockIdx.y * 128;
    const int bn   = blockIdx.x * 128;
    const int sr   = t >> 2;             // staging row 0..63 (2 halves)
    const int sc   = (t & 3) << 3;       // staging col {0,8,16,24}

    f32x4 acc[4][4];
    #pragma unroll
    for (int i = 0; i < 4; i++)
        #pragma unroll
        for (int j = 0; j < 4; j++) {
            f32x4 z = {0.f, 0.f, 0.f, 0.f};
            acc[i][j] = z;
        }

    for (int k0 = 0; k0 < K; k0 += 32) {
        __syncthreads();
        // ---- stage A (rows bm+sr, bm+sr+64; cols k0+sc .. +7) ----
        if (AF32) {
            const float* A = (const float*)Ap;
            const float* p0 = &A[(size_t)(bm + sr) * K + k0 + sc];
            const float* p1 = &A[(size_t)(bm + sr + 64) * K + k0 + sc];
            float4 a0 = *(const float4*)p0, a1 = *(const float4*)(p0 + 4);
            float4 b0 = *(const float4*)p1, b1 = *(const float4*)(p1 + 4);
            *(uint4*)&As[sr][sc] = make_uint4(
                pk_bf16(a0.x, a0.y), pk_bf16(a0.z, a0.w),
                pk_bf16(a1.x, a1.y), pk_bf16(a1.z, a1.w));
            *(uint4*)&As[sr + 64][sc] = make_uint4(
                pk_bf16(b0.x, b0.y), pk_bf16(b0.z, b0.w),
                pk_bf16(b1.x, b1.y), pk_bf16(b1.z, b1.w));
        } else {
            const ushort_t* A = (const ushort_t*)Ap;
            *(uint4*)&As[sr][sc]      = *(const uint4*)&A[(size_t)(bm + sr) * K + k0 + sc];
            *(uint4*)&As[sr + 64][sc] = *(const uint4*)&A[(size_t)(bm + sr + 64) * K + k0 + sc];
        }
        // ---- stage B ----
        if (BF32) {
            const float* B = (const float*)Bp;
            const float* p0 = &B[(size_t)(bn + sr) * K + k0 + sc];
            const float* p1 = &B[(size_t)(bn + sr + 64) * K + k0 + sc];
            float4 a0 = *(const float4*)p0, a1 = *(const float4*)(p0 + 4);
            float4 b0 = *(const float4*)p1, b1 = *(const float4*)(p1 + 4);
            *(uint4*)&Bs[sr][sc] = make_uint4(
                pk_bf16(a0.x, a0.y), pk_bf16(a0.z, a0.w),
                pk_bf16(a1.x, a1.y), pk_bf16(a1.z, a1.w));
            *(uint4*)&Bs[sr + 64][sc] = make_uint4(
                pk_bf16(b0.x, b0.y), pk_bf16(b0.z, b0.w),
                pk_bf16(b1.x, b1.y), pk_bf16(b1.z, b1.w));
        } else {
            const ushort_t* B = (const ushort_t*)Bp;
            *(uint4*)&Bs[sr][sc]      = *(const uint4*)&B[(size_t)(bn + sr) * K + k0 + sc];
            *(uint4*)&Bs[sr + 64][sc] = *(const uint4*)&B[(size_t)(bn + sr + 64) * K + k0 + sc];
        }
        __syncthreads();

        bf16x8 af[4], bfr[4];
        #pragma unroll
        for (int i = 0; i < 4; i++)
            af[i] = *(const bf16x8*)&As[wm + i * 16 + l16][quad * 8];
        #pragma unroll
        for (int j = 0; j < 4; j++)
            bfr[j] = *(const bf16x8*)&Bs[wn + j * 16 + l16][quad * 8];

        #pragma unroll
        for (int i = 0; i < 4; i++)
            #pragma unroll
            for (int j = 0; j < 4; j++)
                acc[i][j] = __builtin_amdgcn_mfma_f32_16x16x32_bf16(
                    af[i], bfr[j], acc[i][j], 0, 0, 0);
    }

    // Epilogue: C/D layout col=lane&15, row=quad*4+reg
    #pragma unroll
    for (int i = 0; i < 4; i++)
        #pragma unroll
        for (int j = 0; j < 4; j++)
            #pragma unroll
            for (int r = 0; r < 4; r++) {
                int row = bm + wm + i * 16 + quad * 4 + r;
                int col = bn + wn + j * 16 + l16;
                if (CF32)
                    ((float*)Cp)[(size_t)row * N + col] = acc[i][j][r];
                else
                    ((ushort_t*)Cp)[(size_t)row * N + col] = f2bf(acc[i][j][r]);
            }
}

// ---------------------------------------------------------------------------
// RoPE in-place on q (heads 0..31) and k (heads 32..39) of bf16 qkv[s][3072].
// cos/sin are fp32 inputs.
// ---------------------------------------------------------------------------
__global__ __launch_bounds__(256) void rope_kernel(
    ushort_t* __restrict__ qkv, const float* __restrict__ cs,
    const float* __restrict__ sn) {
    int idx = blockIdx.x * 256 + threadIdx.x;
    if (idx >= S_LEN * (NQH + NKVH)) return;
    int s  = idx / (NQH + NKVH);
    int hh = idx - s * (NQH + NKVH);

    ushort_t* p = &qkv[(size_t)s * QKV_O + hh * HD];
    const uint4* p4 = (const uint4*)p;
    float v[HD], c[HD], sv[HD];
    #pragma unroll
    for (int b = 0; b < 8; b++) unpack8(&v[b * 8], p4[b]);
    const float4* c4 = (const float4*)&cs[s * HD];
    const float4* s4 = (const float4*)&sn[s * HD];
    #pragma unroll
    for (int b = 0; b < 16; b++) {
        ((float4*)c)[b]  = c4[b];
        ((float4*)sv)[b] = s4[b];
    }
    float o[HD];
    #pragma unroll
    for (int d = 0; d < 32; d++) {
        o[d]      = v[d] * c[d]           - v[d + 32] * sv[d];
        o[d + 32] = v[d + 32] * c[d + 32] + v[d]      * sv[d + 32];
    }
    unsigned int* pw = (unsigned int*)p;
    #pragma unroll
    for (int d = 0; d < HD; d += 2)
        pw[d >> 1] = pk_bf16(o[d], o[d + 1]);
}

// ---------------------------------------------------------------------------
// Causal GQA flash attention (VALU baseline). One thread = one q row;
// block = 256 rows of one head; KV tiles 64x64 staged to LDS as fp32
// (all threads sweep the same K/V row -> LDS broadcast, no conflicts).
// qkv is bf16 workspace; output attnO is bf16 workspace.
// ---------------------------------------------------------------------------
__global__ __launch_bounds__(256) void attn_kernel(
    const ushort_t* __restrict__ qkv, ushort_t* __restrict__ O) {
    const int h   = blockIdx.y;
    const int kvh = h >> 2;                 // group size 4
    const int r0  = blockIdx.x * 256;
    const int tid = threadIdx.x;
    const int i   = r0 + tid;               // this thread's q row

    __shared__ float Ks[64][HD];            // 16 KB
    __shared__ float Vs[64][HD];            // 16 KB

    float q[HD];
    {
        const uint4* q4 = (const uint4*)&qkv[(size_t)i * QKV_O + h * HD];
        #pragma unroll
        for (int b = 0; b < 8; b++) unpack8(&q[b * 8], q4[b]);
        #pragma unroll
        for (int d = 0; d < HD; d++) q[d] *= 0.125f;   // 1/sqrt(64)
    }

    float o[HD];
    #pragma unroll
    for (int d = 0; d < HD; d++) o[d] = 0.f;
    float m = -1e30f, l = 0.f;

    const int jmax = r0 + 256;              // block-uniform KV bound
    const int sr  = tid >> 2;               // staging row 0..63
    const int sc2 = (tid & 3) << 4;         // staging col {0,16,32,48}

    for (int j0 = 0; j0 < jmax; j0 += 64) {
        __syncthreads();
        {
            const ushort_t* kp = &qkv[(size_t)(j0 + sr) * QKV_O + K_COL + kvh * HD + sc2];
            const ushort_t* vp = &qkv[(size_t)(j0 + sr) * QKV_O + V_COL + kvh * HD + sc2];
            uint4 ka = *(const uint4*)kp, kb = *(const uint4*)(kp + 8);
            uint4 va = *(const uint4*)vp, vb = *(const uint4*)(vp + 8);
            unpack8(&Ks[sr][sc2], ka);     unpack8(&Ks[sr][sc2 + 8], kb);
            unpack8(&Vs[sr][sc2], va);     unpack8(&Vs[sr][sc2 + 8], vb);
        }
        __syncthreads();

        for (int jj = 0; jj < 64; jj++) {
            int j = j0 + jj;
            if (j > i) break;               // causal; outer loop still syncs

            const float4* kr = (const float4*)&Ks[jj][0];
            float s0 = 0.f, s1 = 0.f, s2 = 0.f, s3 = 0.f;
            #pragma unroll
            for (int c = 0; c < 16; c += 4) {
                float4 a = kr[c + 0], b = kr[c + 1], cc = kr[c + 2], dd = kr[c + 3];
                s0 = fmaf(q[4*c + 0],  a.x, s0); s0 = fmaf(q[4*c + 1],  a.y, s0);
                s0 = fmaf(q[4*c + 2],  a.z, s0); s0 = fmaf(q[4*c + 3],  a.w, s0);
                s1 = fmaf(q[4*c + 4],  b.x, s1); s1 = fmaf(q[4*c + 5],  b.y, s1);
                s1 = fmaf(q[4*c + 6],  b.z, s1); s1 = fmaf(q[4*c + 7],  b.w, s1);
                s2 = fmaf(q[4*c + 8],  cc.x, s2); s2 = fmaf(q[4*c + 9],  cc.y, s2);
                s2 = fmaf(q[4*c + 10], cc.z, s2); s2 = fmaf(q[4*c + 11], cc.w, s2);
                s3 = fmaf(q[4*c + 12], dd.x, s3); s3 = fmaf(q[4*c + 13], dd.y, s3);
                s3 = fmaf(q[4*c + 14], dd.z, s3); s3 = fmaf(q[4*c + 15], dd.w, s3);
            }
            float s = (s0 + s1) + (s2 + s3);

            float mn   = fmaxf(m, s);
            float corr = __expf(m - mn);
            float p    = __expf(s - mn);
            l = l * corr + p;
            m = mn;

            const float4* vr = (const float4*)&Vs[jj][0];
            #pragma unroll
            for (int c = 0; c < 16; c++) {
                float4 v4 = vr[c];
                o[4*c + 0] = o[4*c + 0] * corr + p * v4.x;
                o[4*c + 1] = o[4*c + 1] * corr + p * v4.y;
                o[4*c + 2] = o[4*c + 2] * corr + p * v4.z;
                o[4*c + 3] = o[4*c + 3] * corr + p * v4.w;
            }
        }
    }

    const float inv = 1.0f / l;
    ushort_t* orow = &O[(size_t)i * (NQH * HD) + h * HD];
    unsigned int* ow = (unsigned int*)orow;
    #pragma unroll
    for (int d = 0; d < HD; d += 2)
        ow[d >> 1] = pk_bf16(o[d] * inv, o[d + 1] * inv);
}

// ---------------------------------------------------------------------------
extern "C" void kernel_launch(void* const* d_in, const int* in_sizes, int n_in,
                              void* d_out, int out_size, void* d_ws, size_t ws_size,
                              hipStream_t stream) {
    const float* x     = (const float*)d_in[0];  // [2048][2048] fp32
    const float* cosp  = (const float*)d_in[1];  // [2048][64]   fp32
    const float* sinp  = (const float*)d_in[2];  // [2048][64]   fp32
    const float* w_qkv = (const float*)d_in[3];  // [3072][2048] fp32
    const float* w_out = (const float*)d_in[4];  // [2048][2048] fp32
    float* out = (float*)d_out;                  // [2048][2048] fp32

    ushort_t* qkv   = (ushort_t*)d_ws;                 // bf16 [2048][3072] (12.6 MB)
    ushort_t* attnO = qkv + (size_t)S_LEN * QKV_O;     // bf16 [2048][2048] (8.4 MB)

    // 1) qkv = x @ w_qkv^T   (fp32 in -> bf16 out)
    dim3 g1(QKV_O / 128, S_LEN / 128);
    gemm_bt<true, true, false><<<g1, 256, 0, stream>>>(x, w_qkv, qkv, S_LEN, QKV_O, HID);

    // 2) RoPE in-place on q/k heads
    int rope_threads = S_LEN * (NQH + NKVH);
    rope_kernel<<<(rope_threads + 255) / 256, 256, 0, stream>>>(qkv, cosp, sinp);

    // 3) causal GQA attention -> attnO[s][h*64+d] (bf16)
    dim3 ga(S_LEN / 256, NQH);
    attn_kernel<<<ga, 256, 0, stream>>>(qkv, attnO);

    // 4) out = attnO @ w_out^T  (bf16 x fp32 -> fp32 out)
    dim3 g2(HID / 128, S_LEN / 128);
    gemm_bt<false, true, true><<<g2, 256, 0, stream>>>(attnO, w_out, out, S_LEN, HID, HID);
}

// Round 4
// 328.234 us; speedup vs baseline: 5.3606x; 5.3606x over previous
//
#include <hip/hip_runtime.h>
#include <hip/hip_bf16.h>
#include <stdint.h>

// Problem constants (B=1). I/O dtype: fp32. Internals bf16 (MFMA path).
#define S_LEN 2048
#define HID   2048
#define NQH   32
#define NKVH  8
#define HD    64
#define QKV_O 3072      // (32 + 2*8) * 64
#define K_COL 2048      // col offset of K block in qkv row
#define V_COL 2560      // col offset of V block in qkv row

typedef unsigned short ushort_t;
typedef __bf16 bf16x8 __attribute__((ext_vector_type(8)));
typedef float  f32x4  __attribute__((ext_vector_type(4)));

__device__ __forceinline__ ushort_t f2bf(float f) {
    unsigned int x = __float_as_uint(f);
    unsigned int r = (x + 0x7fffu + ((x >> 16) & 1u)) >> 16;   // RNE
    return (ushort_t)r;
}
__device__ __forceinline__ unsigned int pk_bf16(float a, float b) {
    __hip_bfloat162 h = __float22bfloat162_rn(make_float2(a, b));
    unsigned int r;
    __builtin_memcpy(&r, &h, 4);
    return r;
}
__device__ __forceinline__ void unpack8(float* dst, uint4 u) {
    dst[0] = __uint_as_float(u.x << 16); dst[1] = __uint_as_float(u.x & 0xffff0000u);
    dst[2] = __uint_as_float(u.y << 16); dst[3] = __uint_as_float(u.y & 0xffff0000u);
    dst[4] = __uint_as_float(u.z << 16); dst[5] = __uint_as_float(u.z & 0xffff0000u);
    dst[6] = __uint_as_float(u.w << 16); dst[7] = __uint_as_float(u.w & 0xffff0000u);
}

// ---------------------------------------------------------------------------
// GEMM: C[M][N] = A[M][K] * Bt[N][K]^T, bf16 MFMA core, fp32 accumulate.
// (unchanged from round 3 — passed; ~65+40 us, next round's target)
// ---------------------------------------------------------------------------
template<bool AF32, bool BF32, bool CF32>
__global__ __launch_bounds__(256) void gemm_bt(
    const void* __restrict__ Ap, const void* __restrict__ Bp,
    void* __restrict__ Cp, int M, int N, int K) {
    __shared__ ushort_t As[128][40];
    __shared__ ushort_t Bs[128][40];

    const int t    = threadIdx.x;
    const int wave = t >> 6;
    const int lane = t & 63;
    const int quad = lane >> 4;
    const int l16  = lane & 15;
    const int wm   = (wave >> 1) << 6;
    const int wn   = (wave & 1)  << 6;
    const int bm   = blockIdx.y * 128;
    const int bn   = blockIdx.x * 128;
    const int sr   = t >> 2;
    const int sc   = (t & 3) << 3;

    f32x4 acc[4][4];
    #pragma unroll
    for (int i = 0; i < 4; i++)
        #pragma unroll
        for (int j = 0; j < 4; j++) {
            f32x4 z = {0.f, 0.f, 0.f, 0.f};
            acc[i][j] = z;
        }

    for (int k0 = 0; k0 < K; k0 += 32) {
        __syncthreads();
        if (AF32) {
            const float* A = (const float*)Ap;
            const float* p0 = &A[(size_t)(bm + sr) * K + k0 + sc];
            const float* p1 = &A[(size_t)(bm + sr + 64) * K + k0 + sc];
            float4 a0 = *(const float4*)p0, a1 = *(const float4*)(p0 + 4);
            float4 b0 = *(const float4*)p1, b1 = *(const float4*)(p1 + 4);
            *(uint4*)&As[sr][sc] = make_uint4(
                pk_bf16(a0.x, a0.y), pk_bf16(a0.z, a0.w),
                pk_bf16(a1.x, a1.y), pk_bf16(a1.z, a1.w));
            *(uint4*)&As[sr + 64][sc] = make_uint4(
                pk_bf16(b0.x, b0.y), pk_bf16(b0.z, b0.w),
                pk_bf16(b1.x, b1.y), pk_bf16(b1.z, b1.w));
        } else {
            const ushort_t* A = (const ushort_t*)Ap;
            *(uint4*)&As[sr][sc]      = *(const uint4*)&A[(size_t)(bm + sr) * K + k0 + sc];
            *(uint4*)&As[sr + 64][sc] = *(const uint4*)&A[(size_t)(bm + sr + 64) * K + k0 + sc];
        }
        if (BF32) {
            const float* B = (const float*)Bp;
            const float* p0 = &B[(size_t)(bn + sr) * K + k0 + sc];
            const float* p1 = &B[(size_t)(bn + sr + 64) * K + k0 + sc];
            float4 a0 = *(const float4*)p0, a1 = *(const float4*)(p0 + 4);
            float4 b0 = *(const float4*)p1, b1 = *(const float4*)(p1 + 4);
            *(uint4*)&Bs[sr][sc] = make_uint4(
                pk_bf16(a0.x, a0.y), pk_bf16(a0.z, a0.w),
                pk_bf16(a1.x, a1.y), pk_bf16(a1.z, a1.w));
            *(uint4*)&Bs[sr + 64][sc] = make_uint4(
                pk_bf16(b0.x, b0.y), pk_bf16(b0.z, b0.w),
                pk_bf16(b1.x, b1.y), pk_bf16(b1.z, b1.w));
        } else {
            const ushort_t* B = (const ushort_t*)Bp;
            *(uint4*)&Bs[sr][sc]      = *(const uint4*)&B[(size_t)(bn + sr) * K + k0 + sc];
            *(uint4*)&Bs[sr + 64][sc] = *(const uint4*)&B[(size_t)(bn + sr + 64) * K + k0 + sc];
        }
        __syncthreads();

        bf16x8 af[4], bfr[4];
        #pragma unroll
        for (int i = 0; i < 4; i++)
            af[i] = *(const bf16x8*)&As[wm + i * 16 + l16][quad * 8];
        #pragma unroll
        for (int j = 0; j < 4; j++)
            bfr[j] = *(const bf16x8*)&Bs[wn + j * 16 + l16][quad * 8];

        #pragma unroll
        for (int i = 0; i < 4; i++)
            #pragma unroll
            for (int j = 0; j < 4; j++)
                acc[i][j] = __builtin_amdgcn_mfma_f32_16x16x32_bf16(
                    af[i], bfr[j], acc[i][j], 0, 0, 0);
    }

    #pragma unroll
    for (int i = 0; i < 4; i++)
        #pragma unroll
        for (int j = 0; j < 4; j++)
            #pragma unroll
            for (int r = 0; r < 4; r++) {
                int row = bm + wm + i * 16 + quad * 4 + r;
                int col = bn + wn + j * 16 + l16;
                if (CF32)
                    ((float*)Cp)[(size_t)row * N + col] = acc[i][j][r];
                else
                    ((ushort_t*)Cp)[(size_t)row * N + col] = f2bf(acc[i][j][r]);
            }
}

// ---------------------------------------------------------------------------
// RoPE in-place (unchanged from round 3)
// ---------------------------------------------------------------------------
__global__ __launch_bounds__(256) void rope_kernel(
    ushort_t* __restrict__ qkv, const float* __restrict__ cs,
    const float* __restrict__ sn) {
    int idx = blockIdx.x * 256 + threadIdx.x;
    if (idx >= S_LEN * (NQH + NKVH)) return;
    int s  = idx / (NQH + NKVH);
    int hh = idx - s * (NQH + NKVH);

    ushort_t* p = &qkv[(size_t)s * QKV_O + hh * HD];
    const uint4* p4 = (const uint4*)p;
    float v[HD], c[HD], sv[HD];
    #pragma unroll
    for (int b = 0; b < 8; b++) unpack8(&v[b * 8], p4[b]);
    const float4* c4 = (const float4*)&cs[s * HD];
    const float4* s4 = (const float4*)&sn[s * HD];
    #pragma unroll
    for (int b = 0; b < 16; b++) {
        ((float4*)c)[b]  = c4[b];
        ((float4*)sv)[b] = s4[b];
    }
    float o[HD];
    #pragma unroll
    for (int d = 0; d < 32; d++) {
        o[d]      = v[d] * c[d]           - v[d + 32] * sv[d];
        o[d + 32] = v[d + 32] * c[d + 32] + v[d]      * sv[d + 32];
    }
    unsigned int* pw = (unsigned int*)p;
    #pragma unroll
    for (int d = 0; d < HD; d += 2)
        pw[d >> 1] = pk_bf16(o[d], o[d + 1]);
}

// ---------------------------------------------------------------------------
// MFMA causal GQA flash attention.
// Block = 1 head x 128 Q rows; 4 waves, each wave owns 32 Q rows (Q frags in
// registers, pre-scaled by 1/8). Per 64-row K tile:
//   QK^T (16 mfma_16x16x32_bf16) -> mask+exp (m=0: scores are O(1), fp32-safe)
//   -> P bf16 via LDS round-trip (C-layout -> A-layout) -> PV (16 MFMA).
// Row-sum l via MFMA against all-ones B fragment (no cross-lane shuffles).
// LDS stride 72 elems = 144 B (16B-aligned, bank-floor).
// ---------------------------------------------------------------------------
__global__ __launch_bounds__(256) void attn_mfma(
    const ushort_t* __restrict__ qkv, ushort_t* __restrict__ O) {
    const int h    = blockIdx.y;
    const int kvh  = h >> 2;                       // GQA group size 4
    const int qt   = (int)gridDim.x - 1 - (int)blockIdx.x;  // deep tiles first
    const int q0   = qt * 128;
    const int tid  = threadIdx.x;
    const int wave = tid >> 6;
    const int lane = tid & 63;
    const int quad = lane >> 4;
    const int l16  = lane & 15;
    const int wq0  = q0 + wave * 32;               // this wave's first Q row

    __shared__ __align__(16) ushort_t Ks[64][72];      // K tile  [krow][d]
    __shared__ __align__(16) ushort_t Vt[64][72];      // V tile T [d][krow]
    __shared__ __align__(16) ushort_t Pl[4][32][72];   // per-wave P [qrow][kcol]

    // Q fragments (resident, scaled by 1/sqrt(64) = 0.125: exact in bf16)
    bf16x8 aq[2][2];
    #pragma unroll
    for (int mi = 0; mi < 2; mi++)
        #pragma unroll
        for (int ks = 0; ks < 2; ks++) {
            uint4 u = *(const uint4*)&qkv[(size_t)(wq0 + mi * 16 + l16) * QKV_O
                                          + h * HD + ks * 32 + quad * 8];
            float f[8]; unpack8(f, u);
            uint4 w = make_uint4(
                pk_bf16(f[0] * 0.125f, f[1] * 0.125f),
                pk_bf16(f[2] * 0.125f, f[3] * 0.125f),
                pk_bf16(f[4] * 0.125f, f[5] * 0.125f),
                pk_bf16(f[6] * 0.125f, f[7] * 0.125f));
            __builtin_memcpy(&aq[mi][ks], &w, 16);
        }

    bf16x8 ones;
    #pragma unroll
    for (int e = 0; e < 8; e++) ones[e] = (__bf16)1.0f;

    f32x4 acc_o[2][4];
    f32x4 acc_l[2];
    #pragma unroll
    for (int mi = 0; mi < 2; mi++) {
        f32x4 z = {0.f, 0.f, 0.f, 0.f};
        acc_l[mi] = z;
        #pragma unroll
        for (int n = 0; n < 4; n++) acc_o[mi][n] = z;
    }

    const int nt = q0 / 64 + 2;          // K tiles needed by this block
    const int sr = tid >> 2;             // staging k-row 0..63
    const int sc = (tid & 3) << 4;       // staging d-col {0,16,32,48}

    for (int t = 0; t < nt; t++) {
        const int j0 = t * 64;
        __syncthreads();
        // ---- stage K row-major, V transposed ----
        {
            const ushort_t* kp = &qkv[(size_t)(j0 + sr) * QKV_O + K_COL + kvh * HD + sc];
            *(uint4*)&Ks[sr][sc]     = *(const uint4*)kp;
            *(uint4*)&Ks[sr][sc + 8] = *(const uint4*)(kp + 8);
            const ushort_t* vp = &qkv[(size_t)(j0 + sr) * QKV_O + V_COL + kvh * HD + sc];
            ushort_t tmp[16];
            *(uint4*)&tmp[0] = *(const uint4*)vp;
            *(uint4*)&tmp[8] = *(const uint4*)(vp + 8);
            #pragma unroll
            for (int e = 0; e < 16; e++) Vt[sc + e][sr] = tmp[e];
        }
        __syncthreads();

        if (j0 > wq0 + 31) continue;     // tile entirely above this wave's rows

        // ---- QK^T ----
        f32x4 s[2][4];
        #pragma unroll
        for (int mi = 0; mi < 2; mi++)
            #pragma unroll
            for (int n = 0; n < 4; n++) {
                f32x4 z = {0.f, 0.f, 0.f, 0.f};
                s[mi][n] = z;
            }
        #pragma unroll
        for (int ks = 0; ks < 2; ks++) {
            bf16x8 bk[4];
            #pragma unroll
            for (int n = 0; n < 4; n++)
                bk[n] = *(const bf16x8*)&Ks[n * 16 + l16][ks * 32 + quad * 8];
            #pragma unroll
            for (int mi = 0; mi < 2; mi++)
                #pragma unroll
                for (int n = 0; n < 4; n++)
                    s[mi][n] = __builtin_amdgcn_mfma_f32_16x16x32_bf16(
                        aq[mi][ks], bk[n], s[mi][n], 0, 0, 0);
        }

        // ---- softmax numerator (m=0), causal mask, pack P to LDS ----
        const bool diag = (j0 + 63 > wq0);
        #pragma unroll
        for (int mi = 0; mi < 2; mi++) {
            const int qr = wq0 + mi * 16 + quad * 4;   // + r = global Q row
            #pragma unroll
            for (int n = 0; n < 4; n++) {
                const int jc = j0 + n * 16 + l16;      // global K col
                #pragma unroll
                for (int r = 0; r < 4; r++) {
                    float p = __expf(s[mi][n][r]);
                    if (diag && jc > qr + r) p = 0.f;
                    Pl[wave][mi * 16 + quad * 4 + r][n * 16 + l16] = f2bf(p);
                }
            }
        }

        // ---- PV and l (ones-MFMA row sum) ----
        #pragma unroll
        for (int ks = 0; ks < 2; ks++) {
            bf16x8 ap[2], bv[4];
            #pragma unroll
            for (int mi = 0; mi < 2; mi++)
                ap[mi] = *(const bf16x8*)&Pl[wave][mi * 16 + l16][ks * 32 + quad * 8];
            #pragma unroll
            for (int n = 0; n < 4; n++)
                bv[n] = *(const bf16x8*)&Vt[n * 16 + l16][ks * 32 + quad * 8];
            #pragma unroll
            for (int mi = 0; mi < 2; mi++) {
                acc_l[mi] = __builtin_amdgcn_mfma_f32_16x16x32_bf16(
                    ap[mi], ones, acc_l[mi], 0, 0, 0);
                #pragma unroll
                for (int n = 0; n < 4; n++)
                    acc_o[mi][n] = __builtin_amdgcn_mfma_f32_16x16x32_bf16(
                        ap[mi], bv[n], acc_o[mi][n], 0, 0, 0);
            }
        }
    }

    // ---- epilogue: O / l ----
    #pragma unroll
    for (int mi = 0; mi < 2; mi++) {
        float inv[4];
        #pragma unroll
        for (int r = 0; r < 4; r++) inv[r] = 1.0f / acc_l[mi][r];
        #pragma unroll
        for (int n = 0; n < 4; n++)
            #pragma unroll
            for (int r = 0; r < 4; r++) {
                int row = wq0 + mi * 16 + quad * 4 + r;
                int col = h * HD + n * 16 + l16;
                O[(size_t)row * (NQH * HD) + col] = f2bf(acc_o[mi][n][r] * inv[r]);
            }
    }
}

// ---------------------------------------------------------------------------
extern "C" void kernel_launch(void* const* d_in, const int* in_sizes, int n_in,
                              void* d_out, int out_size, void* d_ws, size_t ws_size,
                              hipStream_t stream) {
    const float* x     = (const float*)d_in[0];  // [2048][2048] fp32
    const float* cosp  = (const float*)d_in[1];  // [2048][64]   fp32
    const float* sinp  = (const float*)d_in[2];  // [2048][64]   fp32
    const float* w_qkv = (const float*)d_in[3];  // [3072][2048] fp32
    const float* w_out = (const float*)d_in[4];  // [2048][2048] fp32
    float* out = (float*)d_out;                  // [2048][2048] fp32

    ushort_t* qkv   = (ushort_t*)d_ws;                 // bf16 [2048][3072]
    ushort_t* attnO = qkv + (size_t)S_LEN * QKV_O;     // bf16 [2048][2048]

    // 1) qkv = x @ w_qkv^T   (fp32 in -> bf16 out)
    dim3 g1(QKV_O / 128, S_LEN / 128);
    gemm_bt<true, true, false><<<g1, 256, 0, stream>>>(x, w_qkv, qkv, S_LEN, QKV_O, HID);

    // 2) RoPE in-place on q/k heads
    int rope_threads = S_LEN * (NQH + NKVH);
    rope_kernel<<<(rope_threads + 255) / 256, 256, 0, stream>>>(qkv, cosp, sinp);

    // 3) causal GQA attention (MFMA) -> attnO[s][h*64+d] (bf16)
    dim3 ga(S_LEN / 128, NQH);
    attn_mfma<<<ga, 256, 0, stream>>>(qkv, attnO);

    // 4) out = attnO @ w_out^T  (bf16 x fp32 -> fp32 out)
    dim3 g2(HID / 128, S_LEN / 128);
    gemm_bt<false, true, true><<<g2, 256, 0, stream>>>(attnO, w_out, out, S_LEN, HID, HID);
}

// Round 5
// 294.829 us; speedup vs baseline: 5.9680x; 1.1133x over previous
//
#include <hip/hip_runtime.h>
#include <hip/hip_bf16.h>
#include <stdint.h>

// Problem constants (B=1). I/O dtype: fp32. Internals bf16 (MFMA path).
#define S_LEN 2048
#define HID   2048
#define NQH   32
#define NKVH  8
#define HD    64
#define QKV_O 3072      // (32 + 2*8) * 64
#define K_COL 2048      // col offset of K block in qkv row
#define V_COL 2560      // col offset of V block in qkv row

typedef unsigned short ushort_t;
typedef __bf16 bf16x8 __attribute__((ext_vector_type(8)));
typedef float  f32x4  __attribute__((ext_vector_type(4)));

#define GLB(p) ((const __attribute__((address_space(1))) void*)(p))
#define LDSP(p) ((__attribute__((address_space(3))) void*)(p))

__device__ __forceinline__ ushort_t f2bf(float f) {
    unsigned int x = __float_as_uint(f);
    unsigned int r = (x + 0x7fffu + ((x >> 16) & 1u)) >> 16;   // RNE
    return (ushort_t)r;
}
__device__ __forceinline__ unsigned int pk_bf16(float a, float b) {
    __hip_bfloat162 h = __float22bfloat162_rn(make_float2(a, b));
    unsigned int r;
    __builtin_memcpy(&r, &h, 4);
    return r;
}
__device__ __forceinline__ void unpack8(float* dst, uint4 u) {
    dst[0] = __uint_as_float(u.x << 16); dst[1] = __uint_as_float(u.x & 0xffff0000u);
    dst[2] = __uint_as_float(u.y << 16); dst[3] = __uint_as_float(u.y & 0xffff0000u);
    dst[4] = __uint_as_float(u.z << 16); dst[5] = __uint_as_float(u.z & 0xffff0000u);
    dst[6] = __uint_as_float(u.w << 16); dst[7] = __uint_as_float(u.w & 0xffff0000u);
}

// ---------------------------------------------------------------------------
// convert3: fp32 -> bf16 for x (4.19M), w_qkv (6.29M), w_out (4.19M).
// 8 elems/thread; section boundaries are block-aligned (524288/8/... % 256==0)
// so branches are block-uniform. Memory-bound: ~88 MB total traffic.
// ---------------------------------------------------------------------------
#define XN8 (S_LEN * HID / 8)          // 524288
#define QN8 (QKV_O * HID / 8)          // 786432
#define ON8 (HID * HID / 8)            // 524288

__global__ __launch_bounds__(256) void convert3(
    const float* __restrict__ x, const float* __restrict__ wq,
    const float* __restrict__ wo, ushort_t* __restrict__ xb,
    ushort_t* __restrict__ wqb, ushort_t* __restrict__ wob) {
    int i = blockIdx.x * 256 + threadIdx.x;
    const float* s; ushort_t* d; int off;
    if (i < XN8)            { s = x;  d = xb;  off = i; }
    else if (i < XN8 + QN8) { s = wq; d = wqb; off = i - XN8; }
    else                    { s = wo; d = wob; off = i - XN8 - QN8; }
    const float4* sp = (const float4*)s + (size_t)off * 2;
    float4 a = sp[0], b = sp[1];
    *(uint4*)(d + (size_t)off * 8) = make_uint4(
        pk_bf16(a.x, a.y), pk_bf16(a.z, a.w),
        pk_bf16(b.x, b.y), pk_bf16(b.z, b.w));
}

// ---------------------------------------------------------------------------
// Pure-bf16 GEMM (m97 structure): C[M][N] = A[M][K] * Bt[N][K]^T.
// 128x128 tile, BK=32, 4 waves 2x2, 4x4 mfma_16x16x32_bf16 per wave.
// Staging via global_load_lds width=16 (wave-uniform LDS base + lane*16 ->
// LDS must be unpadded row-major; 64 B row stride gives 2-way bank aliasing
// on ds_read_b128 which is free [m136]).
// ---------------------------------------------------------------------------
template<bool CF32>
__global__ __launch_bounds__(256) void gemm_lds(
    const ushort_t* __restrict__ A, const ushort_t* __restrict__ Bt,
    void* __restrict__ Cp, int M, int N, int K) {
    __shared__ ushort_t As[128][32];    // 8 KB, NO padding (global_load_lds)
    __shared__ ushort_t Bs[128][32];    // 8 KB

    const int t    = threadIdx.x;
    const int wave = t >> 6;
    const int lane = t & 63;
    const int quad = lane >> 4;
    const int l16  = lane & 15;
    const int wm   = (wave >> 1) << 6;
    const int wn   = (wave & 1)  << 6;
    const int bm   = blockIdx.y * 128;
    const int bn   = blockIdx.x * 128;
    const int lrow = lane >> 2;          // 0..15 (row within 16-row issue)
    const int lcol = (lane & 3) << 3;    // elem col {0,8,16,24}

    f32x4 acc[4][4];
    #pragma unroll
    for (int i = 0; i < 4; i++)
        #pragma unroll
        for (int j = 0; j < 4; j++) {
            f32x4 z = {0.f, 0.f, 0.f, 0.f};
            acc[i][j] = z;
        }

    const ushort_t* a0 = &A[(size_t)(bm + wave * 32 + lrow) * K + lcol];
    const ushort_t* b0 = &Bt[(size_t)(bn + wave * 32 + lrow) * K + lcol];
    const size_t r16 = (size_t)16 * K;

    for (int k0 = 0; k0 < K; k0 += 32) {
        __syncthreads();
        __builtin_amdgcn_global_load_lds(GLB(a0 + k0),       LDSP(&As[wave * 32][0]),      16, 0, 0);
        __builtin_amdgcn_global_load_lds(GLB(a0 + k0 + r16), LDSP(&As[wave * 32 + 16][0]), 16, 0, 0);
        __builtin_amdgcn_global_load_lds(GLB(b0 + k0),       LDSP(&Bs[wave * 32][0]),      16, 0, 0);
        __builtin_amdgcn_global_load_lds(GLB(b0 + k0 + r16), LDSP(&Bs[wave * 32 + 16][0]), 16, 0, 0);
        __syncthreads();   // compiler emits vmcnt(0) drain here

        bf16x8 af[4], bfr[4];
        #pragma unroll
        for (int i = 0; i < 4; i++)
            af[i] = *(const bf16x8*)&As[wm + i * 16 + l16][quad * 8];
        #pragma unroll
        for (int j = 0; j < 4; j++)
            bfr[j] = *(const bf16x8*)&Bs[wn + j * 16 + l16][quad * 8];

        #pragma unroll
        for (int i = 0; i < 4; i++)
            #pragma unroll
            for (int j = 0; j < 4; j++)
                acc[i][j] = __builtin_amdgcn_mfma_f32_16x16x32_bf16(
                    af[i], bfr[j], acc[i][j], 0, 0, 0);
    }

    // Epilogue: C/D layout col=lane&15, row=quad*4+reg
    #pragma unroll
    for (int i = 0; i < 4; i++)
        #pragma unroll
        for (int j = 0; j < 4; j++)
            #pragma unroll
            for (int r = 0; r < 4; r++) {
                int row = bm + wm + i * 16 + quad * 4 + r;
                int col = bn + wn + j * 16 + l16;
                if (CF32)
                    ((float*)Cp)[(size_t)row * N + col] = acc[i][j][r];
                else
                    ((ushort_t*)Cp)[(size_t)row * N + col] = f2bf(acc[i][j][r]);
            }
}

// ---------------------------------------------------------------------------
// Fallback GEMM with fused fp32->bf16 staging (round-4 path; used only when
// ws_size can't hold the bf16 copies).
// ---------------------------------------------------------------------------
template<bool AF32, bool BF32, bool CF32>
__global__ __launch_bounds__(256) void gemm_bt(
    const void* __restrict__ Ap, const void* __restrict__ Bp,
    void* __restrict__ Cp, int M, int N, int K) {
    __shared__ ushort_t As[128][40];
    __shared__ ushort_t Bs[128][40];

    const int t    = threadIdx.x;
    const int wave = t >> 6;
    const int lane = t & 63;
    const int quad = lane >> 4;
    const int l16  = lane & 15;
    const int wm   = (wave >> 1) << 6;
    const int wn   = (wave & 1)  << 6;
    const int bm   = blockIdx.y * 128;
    const int bn   = blockIdx.x * 128;
    const int sr   = t >> 2;
    const int sc   = (t & 3) << 3;

    f32x4 acc[4][4];
    #pragma unroll
    for (int i = 0; i < 4; i++)
        #pragma unroll
        for (int j = 0; j < 4; j++) {
            f32x4 z = {0.f, 0.f, 0.f, 0.f};
            acc[i][j] = z;
        }

    for (int k0 = 0; k0 < K; k0 += 32) {
        __syncthreads();
        if (AF32) {
            const float* A = (const float*)Ap;
            const float* p0 = &A[(size_t)(bm + sr) * K + k0 + sc];
            const float* p1 = &A[(size_t)(bm + sr + 64) * K + k0 + sc];
            float4 a0 = *(const float4*)p0, a1 = *(const float4*)(p0 + 4);
            float4 b0 = *(const float4*)p1, b1 = *(const float4*)(p1 + 4);
            *(uint4*)&As[sr][sc] = make_uint4(
                pk_bf16(a0.x, a0.y), pk_bf16(a0.z, a0.w),
                pk_bf16(a1.x, a1.y), pk_bf16(a1.z, a1.w));
            *(uint4*)&As[sr + 64][sc] = make_uint4(
                pk_bf16(b0.x, b0.y), pk_bf16(b0.z, b0.w),
                pk_bf16(b1.x, b1.y), pk_bf16(b1.z, b1.w));
        } else {
            const ushort_t* A = (const ushort_t*)Ap;
            *(uint4*)&As[sr][sc]      = *(const uint4*)&A[(size_t)(bm + sr) * K + k0 + sc];
            *(uint4*)&As[sr + 64][sc] = *(const uint4*)&A[(size_t)(bm + sr + 64) * K + k0 + sc];
        }
        if (BF32) {
            const float* B = (const float*)Bp;
            const float* p0 = &B[(size_t)(bn + sr) * K + k0 + sc];
            const float* p1 = &B[(size_t)(bn + sr + 64) * K + k0 + sc];
            float4 a0 = *(const float4*)p0, a1 = *(const float4*)(p0 + 4);
            float4 b0 = *(const float4*)p1, b1 = *(const float4*)(p1 + 4);
            *(uint4*)&Bs[sr][sc] = make_uint4(
                pk_bf16(a0.x, a0.y), pk_bf16(a0.z, a0.w),
                pk_bf16(a1.x, a1.y), pk_bf16(a1.z, a1.w));
            *(uint4*)&Bs[sr + 64][sc] = make_uint4(
                pk_bf16(b0.x, b0.y), pk_bf16(b0.z, b0.w),
                pk_bf16(b1.x, b1.y), pk_bf16(b1.z, b1.w));
        } else {
            const ushort_t* B = (const ushort_t*)Bp;
            *(uint4*)&Bs[sr][sc]      = *(const uint4*)&B[(size_t)(bn + sr) * K + k0 + sc];
            *(uint4*)&Bs[sr + 64][sc] = *(const uint4*)&B[(size_t)(bn + sr + 64) * K + k0 + sc];
        }
        __syncthreads();

        bf16x8 af[4], bfr[4];
        #pragma unroll
        for (int i = 0; i < 4; i++)
            af[i] = *(const bf16x8*)&As[wm + i * 16 + l16][quad * 8];
        #pragma unroll
        for (int j = 0; j < 4; j++)
            bfr[j] = *(const bf16x8*)&Bs[wn + j * 16 + l16][quad * 8];

        #pragma unroll
        for (int i = 0; i < 4; i++)
            #pragma unroll
            for (int j = 0; j < 4; j++)
                acc[i][j] = __builtin_amdgcn_mfma_f32_16x16x32_bf16(
                    af[i], bfr[j], acc[i][j], 0, 0, 0);
    }

    #pragma unroll
    for (int i = 0; i < 4; i++)
        #pragma unroll
        for (int j = 0; j < 4; j++)
            #pragma unroll
            for (int r = 0; r < 4; r++) {
                int row = bm + wm + i * 16 + quad * 4 + r;
                int col = bn + wn + j * 16 + l16;
                if (CF32)
                    ((float*)Cp)[(size_t)row * N + col] = acc[i][j][r];
                else
                    ((ushort_t*)Cp)[(size_t)row * N + col] = f2bf(acc[i][j][r]);
            }
}

// ---------------------------------------------------------------------------
// RoPE in-place (unchanged)
// ---------------------------------------------------------------------------
__global__ __launch_bounds__(256) void rope_kernel(
    ushort_t* __restrict__ qkv, const float* __restrict__ cs,
    const float* __restrict__ sn) {
    int idx = blockIdx.x * 256 + threadIdx.x;
    if (idx >= S_LEN * (NQH + NKVH)) return;
    int s  = idx / (NQH + NKVH);
    int hh = idx - s * (NQH + NKVH);

    ushort_t* p = &qkv[(size_t)s * QKV_O + hh * HD];
    const uint4* p4 = (const uint4*)p;
    float v[HD], c[HD], sv[HD];
    #pragma unroll
    for (int b = 0; b < 8; b++) unpack8(&v[b * 8], p4[b]);
    const float4* c4 = (const float4*)&cs[s * HD];
    const float4* s4 = (const float4*)&sn[s * HD];
    #pragma unroll
    for (int b = 0; b < 16; b++) {
        ((float4*)c)[b]  = c4[b];
        ((float4*)sv)[b] = s4[b];
    }
    float o[HD];
    #pragma unroll
    for (int d = 0; d < 32; d++) {
        o[d]      = v[d] * c[d]           - v[d + 32] * sv[d];
        o[d + 32] = v[d + 32] * c[d + 32] + v[d]      * sv[d + 32];
    }
    unsigned int* pw = (unsigned int*)p;
    #pragma unroll
    for (int d = 0; d < HD; d += 2)
        pw[d >> 1] = pk_bf16(o[d], o[d + 1]);
}

// ---------------------------------------------------------------------------
// MFMA causal GQA flash attention (unchanged from round 4 — now < 92 us)
// ---------------------------------------------------------------------------
__global__ __launch_bounds__(256) void attn_mfma(
    const ushort_t* __restrict__ qkv, ushort_t* __restrict__ O) {
    const int h    = blockIdx.y;
    const int kvh  = h >> 2;
    const int qt   = (int)gridDim.x - 1 - (int)blockIdx.x;
    const int q0   = qt * 128;
    const int tid  = threadIdx.x;
    const int wave = tid >> 6;
    const int lane = tid & 63;
    const int quad = lane >> 4;
    const int l16  = lane & 15;
    const int wq0  = q0 + wave * 32;

    __shared__ __align__(16) ushort_t Ks[64][72];
    __shared__ __align__(16) ushort_t Vt[64][72];
    __shared__ __align__(16) ushort_t Pl[4][32][72];

    bf16x8 aq[2][2];
    #pragma unroll
    for (int mi = 0; mi < 2; mi++)
        #pragma unroll
        for (int ks = 0; ks < 2; ks++) {
            uint4 u = *(const uint4*)&qkv[(size_t)(wq0 + mi * 16 + l16) * QKV_O
                                          + h * HD + ks * 32 + quad * 8];
            float f[8]; unpack8(f, u);
            uint4 w = make_uint4(
                pk_bf16(f[0] * 0.125f, f[1] * 0.125f),
                pk_bf16(f[2] * 0.125f, f[3] * 0.125f),
                pk_bf16(f[4] * 0.125f, f[5] * 0.125f),
                pk_bf16(f[6] * 0.125f, f[7] * 0.125f));
            __builtin_memcpy(&aq[mi][ks], &w, 16);
        }

    bf16x8 ones;
    #pragma unroll
    for (int e = 0; e < 8; e++) ones[e] = (__bf16)1.0f;

    f32x4 acc_o[2][4];
    f32x4 acc_l[2];
    #pragma unroll
    for (int mi = 0; mi < 2; mi++) {
        f32x4 z = {0.f, 0.f, 0.f, 0.f};
        acc_l[mi] = z;
        #pragma unroll
        for (int n = 0; n < 4; n++) acc_o[mi][n] = z;
    }

    const int nt = q0 / 64 + 2;
    const int sr = tid >> 2;
    const int sc = (tid & 3) << 4;

    for (int t = 0; t < nt; t++) {
        const int j0 = t * 64;
        __syncthreads();
        {
            const ushort_t* kp = &qkv[(size_t)(j0 + sr) * QKV_O + K_COL + kvh * HD + sc];
            *(uint4*)&Ks[sr][sc]     = *(const uint4*)kp;
            *(uint4*)&Ks[sr][sc + 8] = *(const uint4*)(kp + 8);
            const ushort_t* vp = &qkv[(size_t)(j0 + sr) * QKV_O + V_COL + kvh * HD + sc];
            ushort_t tmp[16];
            *(uint4*)&tmp[0] = *(const uint4*)vp;
            *(uint4*)&tmp[8] = *(const uint4*)(vp + 8);
            #pragma unroll
            for (int e = 0; e < 16; e++) Vt[sc + e][sr] = tmp[e];
        }
        __syncthreads();

        if (j0 > wq0 + 31) continue;

        f32x4 s[2][4];
        #pragma unroll
        for (int mi = 0; mi < 2; mi++)
            #pragma unroll
            for (int n = 0; n < 4; n++) {
                f32x4 z = {0.f, 0.f, 0.f, 0.f};
                s[mi][n] = z;
            }
        #pragma unroll
        for (int ks = 0; ks < 2; ks++) {
            bf16x8 bk[4];
            #pragma unroll
            for (int n = 0; n < 4; n++)
                bk[n] = *(const bf16x8*)&Ks[n * 16 + l16][ks * 32 + quad * 8];
            #pragma unroll
            for (int mi = 0; mi < 2; mi++)
                #pragma unroll
                for (int n = 0; n < 4; n++)
                    s[mi][n] = __builtin_amdgcn_mfma_f32_16x16x32_bf16(
                        aq[mi][ks], bk[n], s[mi][n], 0, 0, 0);
        }

        const bool diag = (j0 + 63 > wq0);
        #pragma unroll
        for (int mi = 0; mi < 2; mi++) {
            const int qr = wq0 + mi * 16 + quad * 4;
            #pragma unroll
            for (int n = 0; n < 4; n++) {
                const int jc = j0 + n * 16 + l16;
                #pragma unroll
                for (int r = 0; r < 4; r++) {
                    float p = __expf(s[mi][n][r]);
                    if (diag && jc > qr + r) p = 0.f;
                    Pl[wave][mi * 16 + quad * 4 + r][n * 16 + l16] = f2bf(p);
                }
            }
        }

        #pragma unroll
        for (int ks = 0; ks < 2; ks++) {
            bf16x8 ap[2], bv[4];
            #pragma unroll
            for (int mi = 0; mi < 2; mi++)
                ap[mi] = *(const bf16x8*)&Pl[wave][mi * 16 + l16][ks * 32 + quad * 8];
            #pragma unroll
            for (int n = 0; n < 4; n++)
                bv[n] = *(const bf16x8*)&Vt[n * 16 + l16][ks * 32 + quad * 8];
            #pragma unroll
            for (int mi = 0; mi < 2; mi++) {
                acc_l[mi] = __builtin_amdgcn_mfma_f32_16x16x32_bf16(
                    ap[mi], ones, acc_l[mi], 0, 0, 0);
                #pragma unroll
                for (int n = 0; n < 4; n++)
                    acc_o[mi][n] = __builtin_amdgcn_mfma_f32_16x16x32_bf16(
                        ap[mi], bv[n], acc_o[mi][n], 0, 0, 0);
            }
        }
    }

    #pragma unroll
    for (int mi = 0; mi < 2; mi++) {
        float inv[4];
        #pragma unroll
        for (int r = 0; r < 4; r++) inv[r] = 1.0f / acc_l[mi][r];
        #pragma unroll
        for (int n = 0; n < 4; n++)
            #pragma unroll
            for (int r = 0; r < 4; r++) {
                int row = wq0 + mi * 16 + quad * 4 + r;
                int col = h * HD + n * 16 + l16;
                O[(size_t)row * (NQH * HD) + col] = f2bf(acc_o[mi][n][r] * inv[r]);
            }
    }
}

// ---------------------------------------------------------------------------
extern "C" void kernel_launch(void* const* d_in, const int* in_sizes, int n_in,
                              void* d_out, int out_size, void* d_ws, size_t ws_size,
                              hipStream_t stream) {
    const float* x     = (const float*)d_in[0];  // [2048][2048] fp32
    const float* cosp  = (const float*)d_in[1];  // [2048][64]   fp32
    const float* sinp  = (const float*)d_in[2];  // [2048][64]   fp32
    const float* w_qkv = (const float*)d_in[3];  // [3072][2048] fp32
    const float* w_out = (const float*)d_in[4];  // [2048][2048] fp32
    float* out = (float*)d_out;                  // [2048][2048] fp32

    const size_t NQKV = (size_t)S_LEN * QKV_O;   // 6291456
    const size_t NH2  = (size_t)S_LEN * HID;     // 4194304
    const size_t need = 2 * (NQKV + NH2) * sizeof(ushort_t);  // 41.9 MB

    ushort_t* qkv = (ushort_t*)d_ws;             // bf16 [2048][3072]

    if (ws_size >= need) {
        // ws layout: qkv | x_bf(=attnO later) | wqkv_bf | wout_bf
        ushort_t* x_bf    = qkv + NQKV;
        ushort_t* attnO   = x_bf;                // disjoint lifetimes
        ushort_t* wqkv_bf = x_bf + NH2;
        ushort_t* wout_bf = wqkv_bf + NQKV;

        // 0) fp32 -> bf16 for x, w_qkv, w_out (memory-bound, ~88 MB)
        convert3<<<XN8 / 256 + QN8 / 256 + ON8 / 256, 256, 0, stream>>>(
            x, w_qkv, w_out, x_bf, wqkv_bf, wout_bf);

        // 1) qkv = x @ w_qkv^T  (pure bf16, global_load_lds staging)
        dim3 g1(QKV_O / 128, S_LEN / 128);
        gemm_lds<false><<<g1, 256, 0, stream>>>(x_bf, wqkv_bf, qkv, S_LEN, QKV_O, HID);

        // 2) RoPE in-place
        int rope_threads = S_LEN * (NQH + NKVH);
        rope_kernel<<<(rope_threads + 255) / 256, 256, 0, stream>>>(qkv, cosp, sinp);

        // 3) attention -> attnO (overwrites x_bf; GEMM1 already consumed it)
        dim3 ga(S_LEN / 128, NQH);
        attn_mfma<<<ga, 256, 0, stream>>>(qkv, attnO);

        // 4) out = attnO @ w_out^T
        dim3 g2(HID / 128, S_LEN / 128);
        gemm_lds<true><<<g2, 256, 0, stream>>>(attnO, wout_bf, out, S_LEN, HID, HID);
    } else {
        // Fallback: round-4 fused-conversion path (21 MB ws)
        ushort_t* attnO = qkv + NQKV;

        dim3 g1(QKV_O / 128, S_LEN / 128);
        gemm_bt<true, true, false><<<g1, 256, 0, stream>>>(x, w_qkv, qkv, S_LEN, QKV_O, HID);

        int rope_threads = S_LEN * (NQH + NKVH);
        rope_kernel<<<(rope_threads + 255) / 256, 256, 0, stream>>>(qkv, cosp, sinp);

        dim3 ga(S_LEN / 128, NQH);
        attn_mfma<<<ga, 256, 0, stream>>>(qkv, attnO);

        dim3 g2(HID / 128, S_LEN / 128);
        gemm_bt<false, true, true><<<g2, 256, 0, stream>>>(attnO, w_out, out, S_LEN, HID, HID);
    }
}

// Round 7
// 267.602 us; speedup vs baseline: 6.5752x; 1.1017x over previous
//
#include <hip/hip_runtime.h>
#include <hip/hip_bf16.h>
#include <stdint.h>

// Problem constants (B=1). I/O dtype: fp32. Internals bf16 (MFMA path).
#define S_LEN 2048
#define HID   2048
#define NQH   32
#define NKVH  8
#define HD    64
#define QKV_O 3072      // (32 + 2*8) * 64
#define K_COL 2048      // col offset of K block in qkv row
#define V_COL 2560      // col offset of V block in qkv row

typedef unsigned short ushort_t;
typedef __bf16 bf16x8 __attribute__((ext_vector_type(8)));
typedef float  f32x4  __attribute__((ext_vector_type(4)));

#define GLB(p) ((const __attribute__((address_space(1))) void*)(p))
#define LDSP(p) ((__attribute__((address_space(3))) void*)(p))

__device__ __forceinline__ ushort_t f2bf(float f) {
    unsigned int x = __float_as_uint(f);
    unsigned int r = (x + 0x7fffu + ((x >> 16) & 1u)) >> 16;   // RNE
    return (ushort_t)r;
}
__device__ __forceinline__ unsigned int pk_bf16(float a, float b) {
    __hip_bfloat162 h = __float22bfloat162_rn(make_float2(a, b));
    unsigned int r;
    __builtin_memcpy(&r, &h, 4);
    return r;
}
__device__ __forceinline__ void unpack8(float* dst, uint4 u) {
    dst[0] = __uint_as_float(u.x << 16); dst[1] = __uint_as_float(u.x & 0xffff0000u);
    dst[2] = __uint_as_float(u.y << 16); dst[3] = __uint_as_float(u.y & 0xffff0000u);
    dst[4] = __uint_as_float(u.z << 16); dst[5] = __uint_as_float(u.z & 0xffff0000u);
    dst[6] = __uint_as_float(u.w << 16); dst[7] = __uint_as_float(u.w & 0xffff0000u);
}

// ---------------------------------------------------------------------------
// convert3: fp32 -> bf16 for x, w_qkv, w_out (unchanged from round 5)
// ---------------------------------------------------------------------------
#define XN8 (S_LEN * HID / 8)          // 524288
#define QN8 (QKV_O * HID / 8)          // 786432
#define ON8 (HID * HID / 8)            // 524288

__global__ __launch_bounds__(256) void convert3(
    const float* __restrict__ x, const float* __restrict__ wq,
    const float* __restrict__ wo, ushort_t* __restrict__ xb,
    ushort_t* __restrict__ wqb, ushort_t* __restrict__ wob) {
    int i = blockIdx.x * 256 + threadIdx.x;
    const float* s; ushort_t* d; int off;
    if (i < XN8)            { s = x;  d = xb;  off = i; }
    else if (i < XN8 + QN8) { s = wq; d = wqb; off = i - XN8; }
    else                    { s = wo; d = wob; off = i - XN8 - QN8; }
    const float4* sp = (const float4*)s + (size_t)off * 2;
    float4 a = sp[0], b = sp[1];
    *(uint4*)(d + (size_t)off * 8) = make_uint4(
        pk_bf16(a.x, a.y), pk_bf16(a.z, a.w),
        pk_bf16(b.x, b.y), pk_bf16(b.z, b.w));
}

// ---------------------------------------------------------------------------
// Pure-bf16 GEMM (m97 structure) — unchanged from round 5 (passed)
// ---------------------------------------------------------------------------
template<bool CF32>
__global__ __launch_bounds__(256) void gemm_lds(
    const ushort_t* __restrict__ A, const ushort_t* __restrict__ Bt,
    void* __restrict__ Cp, int M, int N, int K) {
    __shared__ ushort_t As[128][32];
    __shared__ ushort_t Bs[128][32];

    const int t    = threadIdx.x;
    const int wave = t >> 6;
    const int lane = t & 63;
    const int quad = lane >> 4;
    const int l16  = lane & 15;
    const int wm   = (wave >> 1) << 6;
    const int wn   = (wave & 1)  << 6;
    const int bm   = blockIdx.y * 128;
    const int bn   = blockIdx.x * 128;
    const int lrow = lane >> 2;
    const int lcol = (lane & 3) << 3;

    f32x4 acc[4][4];
    #pragma unroll
    for (int i = 0; i < 4; i++)
        #pragma unroll
        for (int j = 0; j < 4; j++) {
            f32x4 z = {0.f, 0.f, 0.f, 0.f};
            acc[i][j] = z;
        }

    const ushort_t* a0 = &A[(size_t)(bm + wave * 32 + lrow) * K + lcol];
    const ushort_t* b0 = &Bt[(size_t)(bn + wave * 32 + lrow) * K + lcol];
    const size_t r16 = (size_t)16 * K;

    for (int k0 = 0; k0 < K; k0 += 32) {
        __syncthreads();
        __builtin_amdgcn_global_load_lds(GLB(a0 + k0),       LDSP(&As[wave * 32][0]),      16, 0, 0);
        __builtin_amdgcn_global_load_lds(GLB(a0 + k0 + r16), LDSP(&As[wave * 32 + 16][0]), 16, 0, 0);
        __builtin_amdgcn_global_load_lds(GLB(b0 + k0),       LDSP(&Bs[wave * 32][0]),      16, 0, 0);
        __builtin_amdgcn_global_load_lds(GLB(b0 + k0 + r16), LDSP(&Bs[wave * 32 + 16][0]), 16, 0, 0);
        __syncthreads();

        bf16x8 af[4], bfr[4];
        #pragma unroll
        for (int i = 0; i < 4; i++)
            af[i] = *(const bf16x8*)&As[wm + i * 16 + l16][quad * 8];
        #pragma unroll
        for (int j = 0; j < 4; j++)
            bfr[j] = *(const bf16x8*)&Bs[wn + j * 16 + l16][quad * 8];

        #pragma unroll
        for (int i = 0; i < 4; i++)
            #pragma unroll
            for (int j = 0; j < 4; j++)
                acc[i][j] = __builtin_amdgcn_mfma_f32_16x16x32_bf16(
                    af[i], bfr[j], acc[i][j], 0, 0, 0);
    }

    #pragma unroll
    for (int i = 0; i < 4; i++)
        #pragma unroll
        for (int j = 0; j < 4; j++)
            #pragma unroll
            for (int r = 0; r < 4; r++) {
                int row = bm + wm + i * 16 + quad * 4 + r;
                int col = bn + wn + j * 16 + l16;
                if (CF32)
                    ((float*)Cp)[(size_t)row * N + col] = acc[i][j][r];
                else
                    ((ushort_t*)Cp)[(size_t)row * N + col] = f2bf(acc[i][j][r]);
            }
}

// ---------------------------------------------------------------------------
// Fallback GEMM with fused fp32->bf16 staging (small-ws path; unchanged)
// ---------------------------------------------------------------------------
template<bool AF32, bool BF32, bool CF32>
__global__ __launch_bounds__(256) void gemm_bt(
    const void* __restrict__ Ap, const void* __restrict__ Bp,
    void* __restrict__ Cp, int M, int N, int K) {
    __shared__ ushort_t As[128][40];
    __shared__ ushort_t Bs[128][40];

    const int t    = threadIdx.x;
    const int wave = t >> 6;
    const int lane = t & 63;
    const int quad = lane >> 4;
    const int l16  = lane & 15;
    const int wm   = (wave >> 1) << 6;
    const int wn   = (wave & 1)  << 6;
    const int bm   = blockIdx.y * 128;
    const int bn   = blockIdx.x * 128;
    const int sr   = t >> 2;
    const int sc   = (t & 3) << 3;

    f32x4 acc[4][4];
    #pragma unroll
    for (int i = 0; i < 4; i++)
        #pragma unroll
        for (int j = 0; j < 4; j++) {
            f32x4 z = {0.f, 0.f, 0.f, 0.f};
            acc[i][j] = z;
        }

    for (int k0 = 0; k0 < K; k0 += 32) {
        __syncthreads();
        if (AF32) {
            const float* A = (const float*)Ap;
            const float* p0 = &A[(size_t)(bm + sr) * K + k0 + sc];
            const float* p1 = &A[(size_t)(bm + sr + 64) * K + k0 + sc];
            float4 a0 = *(const float4*)p0, a1 = *(const float4*)(p0 + 4);
            float4 b0 = *(const float4*)p1, b1 = *(const float4*)(p1 + 4);
            *(uint4*)&As[sr][sc] = make_uint4(
                pk_bf16(a0.x, a0.y), pk_bf16(a0.z, a0.w),
                pk_bf16(a1.x, a1.y), pk_bf16(a1.z, a1.w));
            *(uint4*)&As[sr + 64][sc] = make_uint4(
                pk_bf16(b0.x, b0.y), pk_bf16(b0.z, b0.w),
                pk_bf16(b1.x, b1.y), pk_bf16(b1.z, b1.w));
        } else {
            const ushort_t* A = (const ushort_t*)Ap;
            *(uint4*)&As[sr][sc]      = *(const uint4*)&A[(size_t)(bm + sr) * K + k0 + sc];
            *(uint4*)&As[sr + 64][sc] = *(const uint4*)&A[(size_t)(bm + sr + 64) * K + k0 + sc];
        }
        if (BF32) {
            const float* B = (const float*)Bp;
            const float* p0 = &B[(size_t)(bn + sr) * K + k0 + sc];
            const float* p1 = &B[(size_t)(bn + sr + 64) * K + k0 + sc];
            float4 a0 = *(const float4*)p0, a1 = *(const float4*)(p0 + 4);
            float4 b0 = *(const float4*)p1, b1 = *(const float4*)(p1 + 4);
            *(uint4*)&Bs[sr][sc] = make_uint4(
                pk_bf16(a0.x, a0.y), pk_bf16(a0.z, a0.w),
                pk_bf16(a1.x, a1.y), pk_bf16(a1.z, a1.w));
            *(uint4*)&Bs[sr + 64][sc] = make_uint4(
                pk_bf16(b0.x, b0.y), pk_bf16(b0.z, b0.w),
                pk_bf16(b1.x, b1.y), pk_bf16(b1.z, b1.w));
        } else {
            const ushort_t* B = (const ushort_t*)Bp;
            *(uint4*)&Bs[sr][sc]      = *(const uint4*)&B[(size_t)(bn + sr) * K + k0 + sc];
            *(uint4*)&Bs[sr + 64][sc] = *(const uint4*)&B[(size_t)(bn + sr + 64) * K + k0 + sc];
        }
        __syncthreads();

        bf16x8 af[4], bfr[4];
        #pragma unroll
        for (int i = 0; i < 4; i++)
            af[i] = *(const bf16x8*)&As[wm + i * 16 + l16][quad * 8];
        #pragma unroll
        for (int j = 0; j < 4; j++)
            bfr[j] = *(const bf16x8*)&Bs[wn + j * 16 + l16][quad * 8];

        #pragma unroll
        for (int i = 0; i < 4; i++)
            #pragma unroll
            for (int j = 0; j < 4; j++)
                acc[i][j] = __builtin_amdgcn_mfma_f32_16x16x32_bf16(
                    af[i], bfr[j], acc[i][j], 0, 0, 0);
    }

    #pragma unroll
    for (int i = 0; i < 4; i++)
        #pragma unroll
        for (int j = 0; j < 4; j++)
            #pragma unroll
            for (int r = 0; r < 4; r++) {
                int row = bm + wm + i * 16 + quad * 4 + r;
                int col = bn + wn + j * 16 + l16;
                if (CF32)
                    ((float*)Cp)[(size_t)row * N + col] = acc[i][j][r];
                else
                    ((ushort_t*)Cp)[(size_t)row * N + col] = f2bf(acc[i][j][r]);
            }
}

// ---------------------------------------------------------------------------
// RoPE in-place (unchanged)
// ---------------------------------------------------------------------------
__global__ __launch_bounds__(256) void rope_kernel(
    ushort_t* __restrict__ qkv, const float* __restrict__ cs,
    const float* __restrict__ sn) {
    int idx = blockIdx.x * 256 + threadIdx.x;
    if (idx >= S_LEN * (NQH + NKVH)) return;
    int s  = idx / (NQH + NKVH);
    int hh = idx - s * (NQH + NKVH);

    ushort_t* p = &qkv[(size_t)s * QKV_O + hh * HD];
    const uint4* p4 = (const uint4*)p;
    float v[HD], c[HD], sv[HD];
    #pragma unroll
    for (int b = 0; b < 8; b++) unpack8(&v[b * 8], p4[b]);
    const float4* c4 = (const float4*)&cs[s * HD];
    const float4* s4 = (const float4*)&sn[s * HD];
    #pragma unroll
    for (int b = 0; b < 16; b++) {
        ((float4*)c)[b]  = c4[b];
        ((float4*)sv)[b] = s4[b];
    }
    float o[HD];
    #pragma unroll
    for (int d = 0; d < 32; d++) {
        o[d]      = v[d] * c[d]           - v[d + 32] * sv[d];
        o[d + 32] = v[d + 32] * c[d + 32] + v[d]      * sv[d + 32];
    }
    unsigned int* pw = (unsigned int*)p;
    #pragma unroll
    for (int d = 0; d < HD; d += 2)
        pw[d >> 1] = pk_bf16(o[d], o[d + 1]);
}

// ---------------------------------------------------------------------------
// attn_v2: MFMA causal GQA flash attention, S^T orientation, 16x16x32 ONLY.
// Block = 1 head x 128 Q rows (grid 512, deep tiles first); 4 waves x 32 rows.
// Per 64-kcol tile:
//   S^T = K·Q^T   (A = K rows, B = Q rows; C-frag row=kcol, col=qrow)
//   exp + causal mask in-register (m=0; scores O(1), fp32-exp safe — verified
//   rounds 4-5), then the 4 regs (consecutive kcol, fixed qrow) store to P
//   row-major as ONE ds_write_b64 (vs 32x b16 in round 5).
//   PV: A-frag = b128 from P rows; B-frag = b128 from rotation-transposed V.
// V staged transposed with col rotation (+8*(d>>3) mod 64): round-5's stride-72
// pattern had 16*36 % 32 == 0 -> 8-way write conflicts (6.05M measured); the
// rotation spreads the 4 sc-groups 8 banks apart -> ~2-way (free), and keeps
// PV B-frag reads as single aligned ds_read_b128 (rot is a multiple of 8).
// Row-sum l via ones-B MFMA (no shuffles).
// ---------------------------------------------------------------------------
__global__ __launch_bounds__(256) void attn_v2(
    const ushort_t* __restrict__ qkv, ushort_t* __restrict__ O) {
    const int bx   = blockIdx.x;            // 512 blocks
    const int h    = bx & 31;               // head
    const int qt   = 15 - (bx >> 5);        // deep Q tiles dispatch first
    const int kvh  = h >> 2;                // GQA group size 4
    const int q0   = qt * 128;
    const int tid  = threadIdx.x;
    const int wave = tid >> 6;
    const int lane = tid & 63;
    const int quad = lane >> 4;
    const int l16  = lane & 15;
    const int wq0  = q0 + wave * 32;        // this wave's 32 Q rows

    __shared__ __align__(16) ushort_t Ks[64][72];      // K tile [kcol][d]    9.2 KB
    __shared__ __align__(16) ushort_t Vt[64][72];      // V^T rot [d][kcol']  9.2 KB
    __shared__ __align__(16) ushort_t Pl[4][32][72];   // per-wave P [qrow][kcol] 18.4 KB

    // Q B-frags (lane l16 = qrow, elems d = ks*32+quad*8+j), pre-scaled 1/8
    bf16x8 bq[2][2];
    #pragma unroll
    for (int mi = 0; mi < 2; mi++)
        #pragma unroll
        for (int ks = 0; ks < 2; ks++) {
            uint4 u = *(const uint4*)&qkv[(size_t)(wq0 + mi * 16 + l16) * QKV_O
                                          + h * HD + ks * 32 + quad * 8];
            float f[8]; unpack8(f, u);
            uint4 w = make_uint4(
                pk_bf16(f[0] * 0.125f, f[1] * 0.125f),
                pk_bf16(f[2] * 0.125f, f[3] * 0.125f),
                pk_bf16(f[4] * 0.125f, f[5] * 0.125f),
                pk_bf16(f[6] * 0.125f, f[7] * 0.125f));
            __builtin_memcpy(&bq[mi][ks], &w, 16);
        }

    bf16x8 ones;
    #pragma unroll
    for (int e = 0; e < 8; e++) ones[e] = (__bf16)1.0f;

    f32x4 acc_o[2][4];
    f32x4 acc_l[2];
    #pragma unroll
    for (int mi = 0; mi < 2; mi++) {
        f32x4 z = {0.f, 0.f, 0.f, 0.f};
        acc_l[mi] = z;
        #pragma unroll
        for (int n = 0; n < 4; n++) acc_o[mi][n] = z;
    }

    const int nt = qt * 2 + 2;           // 64-col K tiles covering 0..q0+127
    const int sr = tid >> 2;             // staging kcol 0..63
    const int sc = (tid & 3) << 4;       // staging d {0,16,32,48}

    for (int t = 0; t < nt; t++) {
        const int j0 = t * 64;
        __syncthreads();
        {   // ---- stage K row-major (b128 writes) ----
            const ushort_t* kp = &qkv[(size_t)(j0 + sr) * QKV_O + K_COL + kvh * HD + sc];
            *(uint4*)&Ks[sr][sc]     = *(const uint4*)kp;
            *(uint4*)&Ks[sr][sc + 8] = *(const uint4*)(kp + 8);
            // ---- stage V transposed with rotated columns ----
            const ushort_t* vp = &qkv[(size_t)(j0 + sr) * QKV_O + V_COL + kvh * HD + sc];
            ushort_t tmp[16];
            *(uint4*)&tmp[0] = *(const uint4*)vp;
            *(uint4*)&tmp[8] = *(const uint4*)(vp + 8);
            #pragma unroll
            for (int e = 0; e < 16; e++) {
                int d = sc + e;
                Vt[d][(sr + 8 * (d >> 3)) & 63] = tmp[e];
            }
        }
        __syncthreads();

        if (j0 > wq0 + 31) continue;     // tile entirely above this wave's rows

        // ---- S^T = K·Q^T :  st[mi][nk] rows=kcol(nk*16+quad*4+r), col=qrow(l16) ----
        f32x4 st[2][4];
        #pragma unroll
        for (int mi = 0; mi < 2; mi++)
            #pragma unroll
            for (int nk = 0; nk < 4; nk++) {
                f32x4 z = {0.f, 0.f, 0.f, 0.f};
                st[mi][nk] = z;
            }
        #pragma unroll
        for (int ks = 0; ks < 2; ks++) {
            bf16x8 ak[4];
            #pragma unroll
            for (int nk = 0; nk < 4; nk++)
                ak[nk] = *(const bf16x8*)&Ks[nk * 16 + l16][ks * 32 + quad * 8];
            #pragma unroll
            for (int mi = 0; mi < 2; mi++)
                #pragma unroll
                for (int nk = 0; nk < 4; nk++)
                    st[mi][nk] = __builtin_amdgcn_mfma_f32_16x16x32_bf16(
                        ak[nk], bq[mi][ks], st[mi][nk], 0, 0, 0);
        }

        // ---- exp + causal mask, b64 P stores (4 consecutive kcol / qrow) ----
        const bool diag = (j0 + 63 > wq0);
        #pragma unroll
        for (int mi = 0; mi < 2; mi++) {
            const int qrow = wq0 + mi * 16 + l16;
            #pragma unroll
            for (int nk = 0; nk < 4; nk++) {
                const int kc0 = j0 + nk * 16 + quad * 4;
                float p[4];
                #pragma unroll
                for (int r = 0; r < 4; r++) {
                    float e = __expf(st[mi][nk][r]);
                    p[r] = (diag && (kc0 + r > qrow)) ? 0.f : e;
                }
                uint2 w2 = make_uint2(pk_bf16(p[0], p[1]), pk_bf16(p[2], p[3]));
                *(uint2*)&Pl[wave][mi * 16 + l16][nk * 16 + quad * 4] = w2;
            }
        }
        // (same-wave LDS write->read: DS ops are in-order per wave; the round-4/5
        //  kernels relied on this same pattern and verified correct)

        // ---- l += P·1 ; O += P·V ----
        #pragma unroll
        for (int ksp = 0; ksp < 2; ksp++) {
            bf16x8 ap[2], bv[4];
            #pragma unroll
            for (int mi = 0; mi < 2; mi++)
                ap[mi] = *(const bf16x8*)&Pl[wave][mi * 16 + l16][ksp * 32 + quad * 8];
            #pragma unroll
            for (int nd = 0; nd < 4; nd++) {
                const int d = nd * 16 + l16;
                bv[nd] = *(const bf16x8*)&Vt[d][(ksp * 32 + quad * 8 + 8 * (d >> 3)) & 63];
            }
            #pragma unroll
            for (int mi = 0; mi < 2; mi++) {
                acc_l[mi] = __builtin_amdgcn_mfma_f32_16x16x32_bf16(
                    ap[mi], ones, acc_l[mi], 0, 0, 0);
                #pragma unroll
                for (int nd = 0; nd < 4; nd++)
                    acc_o[mi][nd] = __builtin_amdgcn_mfma_f32_16x16x32_bf16(
                        ap[mi], bv[nd], acc_o[mi][nd], 0, 0, 0);
            }
        }
    }

    // ---- epilogue: O / l  (C-layout: row=local qrow=quad*4+r, col=l16) ----
    #pragma unroll
    for (int mi = 0; mi < 2; mi++) {
        float inv[4];
        #pragma unroll
        for (int r = 0; r < 4; r++) inv[r] = 1.0f / acc_l[mi][r];
        #pragma unroll
        for (int nd = 0; nd < 4; nd++)
            #pragma unroll
            for (int r = 0; r < 4; r++) {
                int row = wq0 + mi * 16 + quad * 4 + r;
                int col = h * HD + nd * 16 + l16;
                O[(size_t)row * (NQH * HD) + col] = f2bf(acc_o[mi][nd][r] * inv[r]);
            }
    }
}

// ---------------------------------------------------------------------------
extern "C" void kernel_launch(void* const* d_in, const int* in_sizes, int n_in,
                              void* d_out, int out_size, void* d_ws, size_t ws_size,
                              hipStream_t stream) {
    const float* x     = (const float*)d_in[0];  // [2048][2048] fp32
    const float* cosp  = (const float*)d_in[1];  // [2048][64]   fp32
    const float* sinp  = (const float*)d_in[2];  // [2048][64]   fp32
    const float* w_qkv = (const float*)d_in[3];  // [3072][2048] fp32
    const float* w_out = (const float*)d_in[4];  // [2048][2048] fp32
    float* out = (float*)d_out;                  // [2048][2048] fp32

    const size_t NQKV = (size_t)S_LEN * QKV_O;   // 6291456
    const size_t NH2  = (size_t)S_LEN * HID;     // 4194304
    const size_t need = 2 * (NQKV + NH2) * sizeof(ushort_t);  // 41.9 MB

    ushort_t* qkv = (ushort_t*)d_ws;             // bf16 [2048][3072]

    if (ws_size >= need) {
        ushort_t* x_bf    = qkv + NQKV;
        ushort_t* attnO   = x_bf;                // disjoint lifetimes
        ushort_t* wqkv_bf = x_bf + NH2;
        ushort_t* wout_bf = wqkv_bf + NQKV;

        convert3<<<XN8 / 256 + QN8 / 256 + ON8 / 256, 256, 0, stream>>>(
            x, w_qkv, w_out, x_bf, wqkv_bf, wout_bf);

        dim3 g1(QKV_O / 128, S_LEN / 128);
        gemm_lds<false><<<g1, 256, 0, stream>>>(x_bf, wqkv_bf, qkv, S_LEN, QKV_O, HID);

        int rope_threads = S_LEN * (NQH + NKVH);
        rope_kernel<<<(rope_threads + 255) / 256, 256, 0, stream>>>(qkv, cosp, sinp);

        attn_v2<<<(S_LEN / 128) * NQH, 256, 0, stream>>>(qkv, attnO);

        dim3 g2(HID / 128, S_LEN / 128);
        gemm_lds<true><<<g2, 256, 0, stream>>>(attnO, wout_bf, out, S_LEN, HID, HID);
    } else {
        ushort_t* attnO = qkv + NQKV;

        dim3 g1(QKV_O / 128, S_LEN / 128);
        gemm_bt<true, true, false><<<g1, 256, 0, stream>>>(x, w_qkv, qkv, S_LEN, QKV_O, HID);

        int rope_threads = S_LEN * (NQH + NKVH);
        rope_kernel<<<(rope_threads + 255) / 256, 256, 0, stream>>>(qkv, cosp, sinp);

        attn_v2<<<(S_LEN / 128) * NQH, 256, 0, stream>>>(qkv, attnO);

        dim3 g2(HID / 128, S_LEN / 128);
        gemm_bt<false, true, true><<<g2, 256, 0, stream>>>(attnO, w_out, out, S_LEN, HID, HID);
    }
}

// Round 8
// 247.416 us; speedup vs baseline: 7.1117x; 1.0816x over previous
//
#include <hip/hip_runtime.h>
#include <hip/hip_bf16.h>
#include <stdint.h>

// Problem constants (B=1). I/O dtype: fp32. Internals bf16 (MFMA path).
#define S_LEN 2048
#define HID   2048
#define NQH   32
#define NKVH  8
#define HD    64
#define QKV_O 3072      // (32 + 2*8) * 64
#define K_COL 2048      // col offset of K block in qkv row
#define V_COL 2560      // col offset of V block in qkv row

typedef unsigned short ushort_t;
typedef __bf16 bf16x8 __attribute__((ext_vector_type(8)));
typedef float  f32x4  __attribute__((ext_vector_type(4)));

#define GLB(p) ((const __attribute__((address_space(1))) void*)(p))
#define LDSP(p) ((__attribute__((address_space(3))) void*)(p))

__device__ __forceinline__ ushort_t f2bf(float f) {
    unsigned int x = __float_as_uint(f);
    unsigned int r = (x + 0x7fffu + ((x >> 16) & 1u)) >> 16;   // RNE
    return (ushort_t)r;
}
__device__ __forceinline__ unsigned int pk_bf16(float a, float b) {
    __hip_bfloat162 h = __float22bfloat162_rn(make_float2(a, b));
    unsigned int r;
    __builtin_memcpy(&r, &h, 4);
    return r;
}
__device__ __forceinline__ void unpack8(float* dst, uint4 u) {
    dst[0] = __uint_as_float(u.x << 16); dst[1] = __uint_as_float(u.x & 0xffff0000u);
    dst[2] = __uint_as_float(u.y << 16); dst[3] = __uint_as_float(u.y & 0xffff0000u);
    dst[4] = __uint_as_float(u.z << 16); dst[5] = __uint_as_float(u.z & 0xffff0000u);
    dst[6] = __uint_as_float(u.w << 16); dst[7] = __uint_as_float(u.w & 0xffff0000u);
}

// ---------------------------------------------------------------------------
// convert3: fp32 -> bf16 for x, w_qkv, w_out (unchanged from round 5)
// ---------------------------------------------------------------------------
#define XN8 (S_LEN * HID / 8)          // 524288
#define QN8 (QKV_O * HID / 8)          // 786432
#define ON8 (HID * HID / 8)            // 524288

__global__ __launch_bounds__(256) void convert3(
    const float* __restrict__ x, const float* __restrict__ wq,
    const float* __restrict__ wo, ushort_t* __restrict__ xb,
    ushort_t* __restrict__ wqb, ushort_t* __restrict__ wob) {
    int i = blockIdx.x * 256 + threadIdx.x;
    const float* s; ushort_t* d; int off;
    if (i < XN8)            { s = x;  d = xb;  off = i; }
    else if (i < XN8 + QN8) { s = wq; d = wqb; off = i - XN8; }
    else                    { s = wo; d = wob; off = i - XN8 - QN8; }
    const float4* sp = (const float4*)s + (size_t)off * 2;
    float4 a = sp[0], b = sp[1];
    *(uint4*)(d + (size_t)off * 8) = make_uint4(
        pk_bf16(a.x, a.y), pk_bf16(a.z, a.w),
        pk_bf16(b.x, b.y), pk_bf16(b.z, b.w));
}

// ---------------------------------------------------------------------------
// gemm64: pure-bf16 GEMM, 64x128 (MxN) tile, BK=32, global_load_lds staging.
// Round-7's 128x128 tile gave only 384/256 blocks (1.5/1.0 per CU) at
// S=2048 shapes -> grid starvation (m102 regime). 64x128 doubles the grid
// (768/512 blocks = 3/2 per CU) at a small per-MFMA overhead increase.
// 4 waves in 2x2; each wave 32x64 via 2x4 mfma_16x16x32_bf16.
// M%64==0, N%128==0, K%32==0.
// ---------------------------------------------------------------------------
template<bool CF32>
__global__ __launch_bounds__(256) void gemm64(
    const ushort_t* __restrict__ A, const ushort_t* __restrict__ Bt,
    void* __restrict__ Cp, int M, int N, int K) {
    __shared__ ushort_t As[64][32];     // 4 KB, unpadded (global_load_lds)
    __shared__ ushort_t Bs[128][32];    // 8 KB

    const int t    = threadIdx.x;
    const int wave = t >> 6;
    const int lane = t & 63;
    const int quad = lane >> 4;
    const int l16  = lane & 15;
    const int wm   = (wave >> 1) << 5;   // 0 / 32
    const int wn   = (wave & 1)  << 6;   // 0 / 64
    const int bm   = blockIdx.y * 64;
    const int bn   = blockIdx.x * 128;
    const int lrow = lane >> 2;          // 0..15
    const int lcol = (lane & 3) << 3;    // {0,8,16,24}

    f32x4 acc[2][4];
    #pragma unroll
    for (int i = 0; i < 2; i++)
        #pragma unroll
        for (int j = 0; j < 4; j++) {
            f32x4 z = {0.f, 0.f, 0.f, 0.f};
            acc[i][j] = z;
        }

    // staging: A rows wave*16+lrow (covers 0..63); B rows wave*32+lrow, +16
    const ushort_t* a0 = &A[(size_t)(bm + wave * 16 + lrow) * K + lcol];
    const ushort_t* b0 = &Bt[(size_t)(bn + wave * 32 + lrow) * K + lcol];
    const size_t r16 = (size_t)16 * K;

    for (int k0 = 0; k0 < K; k0 += 32) {
        __syncthreads();
        __builtin_amdgcn_global_load_lds(GLB(a0 + k0),       LDSP(&As[wave * 16][0]),      16, 0, 0);
        __builtin_amdgcn_global_load_lds(GLB(b0 + k0),       LDSP(&Bs[wave * 32][0]),      16, 0, 0);
        __builtin_amdgcn_global_load_lds(GLB(b0 + k0 + r16), LDSP(&Bs[wave * 32 + 16][0]), 16, 0, 0);
        __syncthreads();

        bf16x8 af[2], bfr[4];
        #pragma unroll
        for (int i = 0; i < 2; i++)
            af[i] = *(const bf16x8*)&As[wm + i * 16 + l16][quad * 8];
        #pragma unroll
        for (int j = 0; j < 4; j++)
            bfr[j] = *(const bf16x8*)&Bs[wn + j * 16 + l16][quad * 8];

        #pragma unroll
        for (int i = 0; i < 2; i++)
            #pragma unroll
            for (int j = 0; j < 4; j++)
                acc[i][j] = __builtin_amdgcn_mfma_f32_16x16x32_bf16(
                    af[i], bfr[j], acc[i][j], 0, 0, 0);
    }

    // Epilogue: C/D layout col=lane&15, row=quad*4+reg
    #pragma unroll
    for (int i = 0; i < 2; i++)
        #pragma unroll
        for (int j = 0; j < 4; j++)
            #pragma unroll
            for (int r = 0; r < 4; r++) {
                int row = bm + wm + i * 16 + quad * 4 + r;
                int col = bn + wn + j * 16 + l16;
                if (CF32)
                    ((float*)Cp)[(size_t)row * N + col] = acc[i][j][r];
                else
                    ((ushort_t*)Cp)[(size_t)row * N + col] = f2bf(acc[i][j][r]);
            }
}

// ---------------------------------------------------------------------------
// Fallback GEMM with fused fp32->bf16 staging (small-ws path; unchanged)
// ---------------------------------------------------------------------------
template<bool AF32, bool BF32, bool CF32>
__global__ __launch_bounds__(256) void gemm_bt(
    const void* __restrict__ Ap, const void* __restrict__ Bp,
    void* __restrict__ Cp, int M, int N, int K) {
    __shared__ ushort_t As[128][40];
    __shared__ ushort_t Bs[128][40];

    const int t    = threadIdx.x;
    const int wave = t >> 6;
    const int lane = t & 63;
    const int quad = lane >> 4;
    const int l16  = lane & 15;
    const int wm   = (wave >> 1) << 6;
    const int wn   = (wave & 1)  << 6;
    const int bm   = blockIdx.y * 128;
    const int bn   = blockIdx.x * 128;
    const int sr   = t >> 2;
    const int sc   = (t & 3) << 3;

    f32x4 acc[4][4];
    #pragma unroll
    for (int i = 0; i < 4; i++)
        #pragma unroll
        for (int j = 0; j < 4; j++) {
            f32x4 z = {0.f, 0.f, 0.f, 0.f};
            acc[i][j] = z;
        }

    for (int k0 = 0; k0 < K; k0 += 32) {
        __syncthreads();
        if (AF32) {
            const float* A = (const float*)Ap;
            const float* p0 = &A[(size_t)(bm + sr) * K + k0 + sc];
            const float* p1 = &A[(size_t)(bm + sr + 64) * K + k0 + sc];
            float4 a0 = *(const float4*)p0, a1 = *(const float4*)(p0 + 4);
            float4 b0 = *(const float4*)p1, b1 = *(const float4*)(p1 + 4);
            *(uint4*)&As[sr][sc] = make_uint4(
                pk_bf16(a0.x, a0.y), pk_bf16(a0.z, a0.w),
                pk_bf16(a1.x, a1.y), pk_bf16(a1.z, a1.w));
            *(uint4*)&As[sr + 64][sc] = make_uint4(
                pk_bf16(b0.x, b0.y), pk_bf16(b0.z, b0.w),
                pk_bf16(b1.x, b1.y), pk_bf16(b1.z, b1.w));
        } else {
            const ushort_t* A = (const ushort_t*)Ap;
            *(uint4*)&As[sr][sc]      = *(const uint4*)&A[(size_t)(bm + sr) * K + k0 + sc];
            *(uint4*)&As[sr + 64][sc] = *(const uint4*)&A[(size_t)(bm + sr + 64) * K + k0 + sc];
        }
        if (BF32) {
            const float* B = (const float*)Bp;
            const float* p0 = &B[(size_t)(bn + sr) * K + k0 + sc];
            const float* p1 = &B[(size_t)(bn + sr + 64) * K + k0 + sc];
            float4 a0 = *(const float4*)p0, a1 = *(const float4*)(p0 + 4);
            float4 b0 = *(const float4*)p1, b1 = *(const float4*)(p1 + 4);
            *(uint4*)&Bs[sr][sc] = make_uint4(
                pk_bf16(a0.x, a0.y), pk_bf16(a0.z, a0.w),
                pk_bf16(a1.x, a1.y), pk_bf16(a1.z, a1.w));
            *(uint4*)&Bs[sr + 64][sc] = make_uint4(
                pk_bf16(b0.x, b0.y), pk_bf16(b0.z, b0.w),
                pk_bf16(b1.x, b1.y), pk_bf16(b1.z, b1.w));
        } else {
            const ushort_t* B = (const ushort_t*)Bp;
            *(uint4*)&Bs[sr][sc]      = *(const uint4*)&B[(size_t)(bn + sr) * K + k0 + sc];
            *(uint4*)&Bs[sr + 64][sc] = *(const uint4*)&B[(size_t)(bn + sr + 64) * K + k0 + sc];
        }
        __syncthreads();

        bf16x8 af[4], bfr[4];
        #pragma unroll
        for (int i = 0; i < 4; i++)
            af[i] = *(const bf16x8*)&As[wm + i * 16 + l16][quad * 8];
        #pragma unroll
        for (int j = 0; j < 4; j++)
            bfr[j] = *(const bf16x8*)&Bs[wn + j * 16 + l16][quad * 8];

        #pragma unroll
        for (int i = 0; i < 4; i++)
            #pragma unroll
            for (int j = 0; j < 4; j++)
                acc[i][j] = __builtin_amdgcn_mfma_f32_16x16x32_bf16(
                    af[i], bfr[j], acc[i][j], 0, 0, 0);
    }

    #pragma unroll
    for (int i = 0; i < 4; i++)
        #pragma unroll
        for (int j = 0; j < 4; j++)
            #pragma unroll
            for (int r = 0; r < 4; r++) {
                int row = bm + wm + i * 16 + quad * 4 + r;
                int col = bn + wn + j * 16 + l16;
                if (CF32)
                    ((float*)Cp)[(size_t)row * N + col] = acc[i][j][r];
                else
                    ((ushort_t*)Cp)[(size_t)row * N + col] = f2bf(acc[i][j][r]);
            }
}

// ---------------------------------------------------------------------------
// RoPE in-place (unchanged)
// ---------------------------------------------------------------------------
__global__ __launch_bounds__(256) void rope_kernel(
    ushort_t* __restrict__ qkv, const float* __restrict__ cs,
    const float* __restrict__ sn) {
    int idx = blockIdx.x * 256 + threadIdx.x;
    if (idx >= S_LEN * (NQH + NKVH)) return;
    int s  = idx / (NQH + NKVH);
    int hh = idx - s * (NQH + NKVH);

    ushort_t* p = &qkv[(size_t)s * QKV_O + hh * HD];
    const uint4* p4 = (const uint4*)p;
    float v[HD], c[HD], sv[HD];
    #pragma unroll
    for (int b = 0; b < 8; b++) unpack8(&v[b * 8], p4[b]);
    const float4* c4 = (const float4*)&cs[s * HD];
    const float4* s4 = (const float4*)&sn[s * HD];
    #pragma unroll
    for (int b = 0; b < 16; b++) {
        ((float4*)c)[b]  = c4[b];
        ((float4*)sv)[b] = s4[b];
    }
    float o[HD];
    #pragma unroll
    for (int d = 0; d < 32; d++) {
        o[d]      = v[d] * c[d]           - v[d + 32] * sv[d];
        o[d + 32] = v[d + 32] * c[d + 32] + v[d]      * sv[d + 32];
    }
    unsigned int* pw = (unsigned int*)p;
    #pragma unroll
    for (int d = 0; d < HD; d += 2)
        pw[d >> 1] = pk_bf16(o[d], o[d + 1]);
}

// ---------------------------------------------------------------------------
// attn_v2: MFMA causal GQA flash attention (unchanged from round 7 — 62.9 us)
// ---------------------------------------------------------------------------
__global__ __launch_bounds__(256) void attn_v2(
    const ushort_t* __restrict__ qkv, ushort_t* __restrict__ O) {
    const int bx   = blockIdx.x;            // 512 blocks
    const int h    = bx & 31;               // head
    const int qt   = 15 - (bx >> 5);        // deep Q tiles dispatch first
    const int kvh  = h >> 2;                // GQA group size 4
    const int q0   = qt * 128;
    const int tid  = threadIdx.x;
    const int wave = tid >> 6;
    const int lane = tid & 63;
    const int quad = lane >> 4;
    const int l16  = lane & 15;
    const int wq0  = q0 + wave * 32;        // this wave's 32 Q rows

    __shared__ __align__(16) ushort_t Ks[64][72];      // K tile [kcol][d]    9.2 KB
    __shared__ __align__(16) ushort_t Vt[64][72];      // V^T rot [d][kcol']  9.2 KB
    __shared__ __align__(16) ushort_t Pl[4][32][72];   // per-wave P [qrow][kcol] 18.4 KB

    bf16x8 bq[2][2];
    #pragma unroll
    for (int mi = 0; mi < 2; mi++)
        #pragma unroll
        for (int ks = 0; ks < 2; ks++) {
            uint4 u = *(const uint4*)&qkv[(size_t)(wq0 + mi * 16 + l16) * QKV_O
                                          + h * HD + ks * 32 + quad * 8];
            float f[8]; unpack8(f, u);
            uint4 w = make_uint4(
                pk_bf16(f[0] * 0.125f, f[1] * 0.125f),
                pk_bf16(f[2] * 0.125f, f[3] * 0.125f),
                pk_bf16(f[4] * 0.125f, f[5] * 0.125f),
                pk_bf16(f[6] * 0.125f, f[7] * 0.125f));
            __builtin_memcpy(&bq[mi][ks], &w, 16);
        }

    bf16x8 ones;
    #pragma unroll
    for (int e = 0; e < 8; e++) ones[e] = (__bf16)1.0f;

    f32x4 acc_o[2][4];
    f32x4 acc_l[2];
    #pragma unroll
    for (int mi = 0; mi < 2; mi++) {
        f32x4 z = {0.f, 0.f, 0.f, 0.f};
        acc_l[mi] = z;
        #pragma unroll
        for (int n = 0; n < 4; n++) acc_o[mi][n] = z;
    }

    const int nt = qt * 2 + 2;
    const int sr = tid >> 2;
    const int sc = (tid & 3) << 4;

    for (int t = 0; t < nt; t++) {
        const int j0 = t * 64;
        __syncthreads();
        {
            const ushort_t* kp = &qkv[(size_t)(j0 + sr) * QKV_O + K_COL + kvh * HD + sc];
            *(uint4*)&Ks[sr][sc]     = *(const uint4*)kp;
            *(uint4*)&Ks[sr][sc + 8] = *(const uint4*)(kp + 8);
            const ushort_t* vp = &qkv[(size_t)(j0 + sr) * QKV_O + V_COL + kvh * HD + sc];
            ushort_t tmp[16];
            *(uint4*)&tmp[0] = *(const uint4*)vp;
            *(uint4*)&tmp[8] = *(const uint4*)(vp + 8);
            #pragma unroll
            for (int e = 0; e < 16; e++) {
                int d = sc + e;
                Vt[d][(sr + 8 * (d >> 3)) & 63] = tmp[e];
            }
        }
        __syncthreads();

        if (j0 > wq0 + 31) continue;

        f32x4 st[2][4];
        #pragma unroll
        for (int mi = 0; mi < 2; mi++)
            #pragma unroll
            for (int nk = 0; nk < 4; nk++) {
                f32x4 z = {0.f, 0.f, 0.f, 0.f};
                st[mi][nk] = z;
            }
        #pragma unroll
        for (int ks = 0; ks < 2; ks++) {
            bf16x8 ak[4];
            #pragma unroll
            for (int nk = 0; nk < 4; nk++)
                ak[nk] = *(const bf16x8*)&Ks[nk * 16 + l16][ks * 32 + quad * 8];
            #pragma unroll
            for (int mi = 0; mi < 2; mi++)
                #pragma unroll
                for (int nk = 0; nk < 4; nk++)
                    st[mi][nk] = __builtin_amdgcn_mfma_f32_16x16x32_bf16(
                        ak[nk], bq[mi][ks], st[mi][nk], 0, 0, 0);
        }

        const bool diag = (j0 + 63 > wq0);
        #pragma unroll
        for (int mi = 0; mi < 2; mi++) {
            const int qrow = wq0 + mi * 16 + l16;
            #pragma unroll
            for (int nk = 0; nk < 4; nk++) {
                const int kc0 = j0 + nk * 16 + quad * 4;
                float p[4];
                #pragma unroll
                for (int r = 0; r < 4; r++) {
                    float e = __expf(st[mi][nk][r]);
                    p[r] = (diag && (kc0 + r > qrow)) ? 0.f : e;
                }
                uint2 w2 = make_uint2(pk_bf16(p[0], p[1]), pk_bf16(p[2], p[3]));
                *(uint2*)&Pl[wave][mi * 16 + l16][nk * 16 + quad * 4] = w2;
            }
        }

        #pragma unroll
        for (int ksp = 0; ksp < 2; ksp++) {
            bf16x8 ap[2], bv[4];
            #pragma unroll
            for (int mi = 0; mi < 2; mi++)
                ap[mi] = *(const bf16x8*)&Pl[wave][mi * 16 + l16][ksp * 32 + quad * 8];
            #pragma unroll
            for (int nd = 0; nd < 4; nd++) {
                const int d = nd * 16 + l16;
                bv[nd] = *(const bf16x8*)&Vt[d][(ksp * 32 + quad * 8 + 8 * (d >> 3)) & 63];
            }
            #pragma unroll
            for (int mi = 0; mi < 2; mi++) {
                acc_l[mi] = __builtin_amdgcn_mfma_f32_16x16x32_bf16(
                    ap[mi], ones, acc_l[mi], 0, 0, 0);
                #pragma unroll
                for (int nd = 0; nd < 4; nd++)
                    acc_o[mi][nd] = __builtin_amdgcn_mfma_f32_16x16x32_bf16(
                        ap[mi], bv[nd], acc_o[mi][nd], 0, 0, 0);
            }
        }
    }

    #pragma unroll
    for (int mi = 0; mi < 2; mi++) {
        float inv[4];
        #pragma unroll
        for (int r = 0; r < 4; r++) inv[r] = 1.0f / acc_l[mi][r];
        #pragma unroll
        for (int nd = 0; nd < 4; nd++)
            #pragma unroll
            for (int r = 0; r < 4; r++) {
                int row = wq0 + mi * 16 + quad * 4 + r;
                int col = h * HD + nd * 16 + l16;
                O[(size_t)row * (NQH * HD) + col] = f2bf(acc_o[mi][nd][r] * inv[r]);
            }
    }
}

// ---------------------------------------------------------------------------
extern "C" void kernel_launch(void* const* d_in, const int* in_sizes, int n_in,
                              void* d_out, int out_size, void* d_ws, size_t ws_size,
                              hipStream_t stream) {
    const float* x     = (const float*)d_in[0];  // [2048][2048] fp32
    const float* cosp  = (const float*)d_in[1];  // [2048][64]   fp32
    const float* sinp  = (const float*)d_in[2];  // [2048][64]   fp32
    const float* w_qkv = (const float*)d_in[3];  // [3072][2048] fp32
    const float* w_out = (const float*)d_in[4];  // [2048][2048] fp32
    float* out = (float*)d_out;                  // [2048][2048] fp32

    const size_t NQKV = (size_t)S_LEN * QKV_O;   // 6291456
    const size_t NH2  = (size_t)S_LEN * HID;     // 4194304
    const size_t need = 2 * (NQKV + NH2) * sizeof(ushort_t);  // 41.9 MB

    ushort_t* qkv = (ushort_t*)d_ws;             // bf16 [2048][3072]

    if (ws_size >= need) {
        ushort_t* x_bf    = qkv + NQKV;
        ushort_t* attnO   = x_bf;                // disjoint lifetimes
        ushort_t* wqkv_bf = x_bf + NH2;
        ushort_t* wout_bf = wqkv_bf + NQKV;

        convert3<<<XN8 / 256 + QN8 / 256 + ON8 / 256, 256, 0, stream>>>(
            x, w_qkv, w_out, x_bf, wqkv_bf, wout_bf);

        // 1) qkv = x @ w_qkv^T   — 64x128 tiles: 24 x 32 = 768 blocks (3/CU)
        dim3 g1(QKV_O / 128, S_LEN / 64);
        gemm64<false><<<g1, 256, 0, stream>>>(x_bf, wqkv_bf, qkv, S_LEN, QKV_O, HID);

        int rope_threads = S_LEN * (NQH + NKVH);
        rope_kernel<<<(rope_threads + 255) / 256, 256, 0, stream>>>(qkv, cosp, sinp);

        attn_v2<<<(S_LEN / 128) * NQH, 256, 0, stream>>>(qkv, attnO);

        // 4) out = attnO @ w_out^T — 16 x 32 = 512 blocks (2/CU)
        dim3 g2(HID / 128, S_LEN / 64);
        gemm64<true><<<g2, 256, 0, stream>>>(attnO, wout_bf, out, S_LEN, HID, HID);
    } else {
        ushort_t* attnO = qkv + NQKV;

        dim3 g1(QKV_O / 128, S_LEN / 128);
        gemm_bt<true, true, false><<<g1, 256, 0, stream>>>(x, w_qkv, qkv, S_LEN, QKV_O, HID);

        int rope_threads = S_LEN * (NQH + NKVH);
        rope_kernel<<<(rope_threads + 255) / 256, 256, 0, stream>>>(qkv, cosp, sinp);

        attn_v2<<<(S_LEN / 128) * NQH, 256, 0, stream>>>(qkv, attnO);

        dim3 g2(HID / 128, S_LEN / 128);
        gemm_bt<false, true, true><<<g2, 256, 0, stream>>>(attnO, w_out, out, S_LEN, HID, HID);
    }
}